// Round 13
// baseline (180.925 us; speedup 1.0000x reference)
//
#include <hip/hip_runtime.h>
#include <math.h>

#define NBLK 512     // bucketing blocks (each owns a contiguous edge chunk)
#define BSHIFT 7     // 128 nodes per bucket
#define BMASK 127

// ---------------- DPP helpers (full-rate VALU cross-lane, no LDS) ----------------

template<int CTRL>
__device__ __forceinline__ float dppf(float x) {
    return __int_as_float(__builtin_amdgcn_update_dpp(
        0, __float_as_int(x), CTRL, 0xF, 0xF, true));
}
// sum over 4-lane quad (lanes end with identical value)
__device__ __forceinline__ float quadsum(float x) {
    x += dppf<0xB1>(x);   // quad_perm xor 1
    x += dppf<0x4E>(x);   // quad_perm xor 2
    return x;
}
// sum over 16-lane group
__device__ __forceinline__ float sum16(float x) {
    x += dppf<0xB1>(x);
    x += dppf<0x4E>(x);
    x += dppf<0x141>(x);  // row_half_mirror
    x += dppf<0x140>(x);  // row_mirror
    return x;
}

// ---------------- init (replaces pathological hipMemsetAsync fills) ----------------

__global__ void k_init(float* __restrict__ sums, float* __restrict__ cnt, int gn) {
    int i = blockIdx.x * 256 + threadIdx.x;
    if (i < gn * 64) sums[i] = 0.f;
    if (i < gn) cnt[i] = 0.f;
}

// ---------------- Pass 1: per-(bucket,block) histogram, LDS only ----------------

__global__ __launch_bounds__(256) void k_hist(const int* __restrict__ tgt,
                                              int* __restrict__ gh,
                                              int e, int chunk, int nbuck) {
    __shared__ int lh[512];
    int tid = threadIdx.x, blk = blockIdx.x;
    for (int j = tid; j < nbuck; j += 256) lh[j] = 0;
    __syncthreads();
    int lo = blk * chunk, hi = min(lo + chunk, e);
    for (int i = lo + tid; i < hi; i += 256)
        atomicAdd(&lh[tgt[i] >> BSHIFT], 1);
    __syncthreads();
    for (int j = tid; j < nbuck; j += 256) gh[j * NBLK + blk] = lh[j];
}

// ---------------- scan kernels (cell table; boff folded into consumers) ----------------

__global__ __launch_bounds__(256) void k_scanA(const int* __restrict__ deg,
                                               int* __restrict__ excl,
                                               int* __restrict__ bsum, int n) {
    int i = blockIdx.x * 256 + threadIdx.x;
    int lane = threadIdx.x & 63, wv = threadIdx.x >> 6;
    int v = (i < n) ? deg[i] : 0;
    int incl = v;
#pragma unroll
    for (int off = 1; off < 64; off <<= 1) {
        int t = __shfl_up(incl, off);
        if (lane >= off) incl += t;
    }
    __shared__ int ws[4];
    if (lane == 63) ws[wv] = incl;
    __syncthreads();
    int prefix = 0;
    for (int k = 0; k < wv; ++k) prefix += ws[k];
    if (i < n) excl[i] = prefix + incl - v;
    if (threadIdx.x == 255) bsum[blockIdx.x] = prefix + incl;
}

__global__ __launch_bounds__(256) void k_scanB(const int* __restrict__ bsum, int* __restrict__ boff,
                                               int nb) {
    __shared__ int ws[4];
    __shared__ int carry_s;
    int lane = threadIdx.x & 63, wv = threadIdx.x >> 6;
    if (threadIdx.x == 0) carry_s = 0;
    __syncthreads();
    for (int base = 0; base < nb; base += 256) {
        int i = base + threadIdx.x;
        int v = (i < nb) ? bsum[i] : 0;
        int incl = v;
#pragma unroll
        for (int off = 1; off < 64; off <<= 1) {
            int t = __shfl_up(incl, off);
            if (lane >= off) incl += t;
        }
        if (lane == 63) ws[wv] = incl;
        __syncthreads();
        int prefix = carry_s;
        for (int k = 0; k < wv; ++k) prefix += ws[k];
        if (i < nb) boff[i] = prefix + incl - v;
        __syncthreads();
        if (threadIdx.x == 255) carry_s = prefix + incl;
        __syncthreads();
    }
}

// ---------------- Pass 2: block-dense bucket placement (no global atomics) ----------------

__global__ __launch_bounds__(256) void k_binplace(const int* __restrict__ src,
                                                  const int* __restrict__ tgt,
                                                  const float* __restrict__ ea,
                                                  const float* __restrict__ x,
                                                  const int* __restrict__ gexcl,
                                                  const int* __restrict__ gboff,
                                                  float4* __restrict__ brec,
                                                  int* __restrict__ bmeta,
                                                  int e, int chunk, int nbuck) {
    __shared__ int loff[512];
    int tid = threadIdx.x, blk = blockIdx.x;
    for (int j = tid; j < nbuck; j += 256) {
        int cell = j * NBLK + blk;
        loff[j] = gexcl[cell] + gboff[cell >> 8];
    }
    __syncthreads();
    int lo = blk * chunk, hi = min(lo + chunk, e);
    for (int i = lo + tid; i < hi; i += 256) {
        int t = tgt[i], s = src[i];
        float2 ev = ((const float2*)ea)[i];
        float2 xv = *(const float2*)(x + 2 * (size_t)s);
        int dst = atomicAdd(&loff[t >> BSHIFT], 1);
        brec[dst] = make_float4(xv.x, xv.y, ev.x, ev.y);     // {x[src], ea}
        bmeta[dst] = (s & 0xFFFF) | ((t & BMASK) << 16);     // src16 | tgt_local7
    }
}

// ---------------- fused: per-bucket degree hist + scan + rowp + CSR placement ----------------

__global__ __launch_bounds__(256) void k_place2(const int* __restrict__ gexcl,
                                                const int* __restrict__ gboff,
                                                const int* __restrict__ bmeta,
                                                const float4* __restrict__ brec,
                                                float4* __restrict__ col_rec,
                                                int* __restrict__ col_src,
                                                int* __restrict__ rowp,
                                                int n, int ntot, int e) {
    __shared__ int hist[256];
    __shared__ int pos[256];
    __shared__ int ws[4];
    int b = blockIdx.x, tid = threadIdx.x;
    int clo = b * NBLK, chi = clo + NBLK;
    int lo = gexcl[clo] + gboff[clo >> 8];
    int hi = (chi >= ntot) ? e : (gexcl[chi] + gboff[chi >> 8]);
    hist[tid] = 0;
    __syncthreads();
    for (int i = lo + tid; i < hi; i += 256)
        atomicAdd(&hist[(bmeta[i] >> 16) & BMASK], 1);
    __syncthreads();
    int lane = tid & 63, wv = tid >> 6;
    int v = hist[tid];
    int incl = v;
#pragma unroll
    for (int off = 1; off < 64; off <<= 1) {
        int t = __shfl_up(incl, off);
        if (lane >= off) incl += t;
    }
    if (lane == 63) ws[wv] = incl;
    __syncthreads();
    int prefix = 0;
    for (int k = 0; k < wv; ++k) prefix += ws[k];
    int rp = lo + prefix + incl - v;
    int node = b * 128 + tid;
    if (tid < 128 && node <= n) rowp[node] = rp;
    if (b == (int)gridDim.x - 1 && tid == 0) rowp[n] = hi;
    pos[tid] = rp;
    __syncthreads();
    for (int i = lo + tid; i < hi; i += 256) {
        int m = bmeta[i];
        float4 r = brec[i];
        int slot = atomicAdd(&pos[(m >> 16) & BMASK], 1);
        col_rec[slot] = r;
        col_src[slot] = m & 0xFFFF;
    }
}

// ---------------- Layer 1: linearized no-max softmax aggregation ----------------
// wave per node; lane l owns features 2l,2l+1; head = l>>2 (4-lane quad groups).
// Output per node: 16 head-pairs q=(px0,px1)/lh (6.4MB) + deg>0 flag. hpost is
// reconstructed on the fly in k_transform2 (saves the 25.6MB hpost round trip).

__global__ __launch_bounds__(256) void k_agg1(
    const float* __restrict__ x,
    const int* __restrict__ rowp,
    const float4* __restrict__ col_rec,
    const float* __restrict__ W_l1, const float* __restrict__ b_l1,
    const float* __restrict__ W_r1, const float* __restrict__ b_r1,
    const float* __restrict__ W_e1,
    const float* __restrict__ att1,
    float2* __restrict__ qbuf,       // [n*16]
    int* __restrict__ flags,         // [n]
    int n)
{
    int wid = (blockIdx.x * blockDim.x + threadIdx.x) >> 6;
    if (wid >= n) return;
    int v = __builtin_amdgcn_readfirstlane(wid);
    int lane = threadIdx.x & 63;
    int f0 = 2 * lane, f1 = 2 * lane + 1;

    float Wl00 = W_l1[f0], Wl10 = W_l1[128 + f0];
    float Wl01 = W_l1[f1], Wl11 = W_l1[128 + f1];
    float We00 = W_e1[f0], We10 = W_e1[128 + f0];
    float We01 = W_e1[f1], We11 = W_e1[128 + f1];
    float a0 = att1[f0], a1 = att1[f1];

    float xv0 = x[2 * v], xv1 = x[2 * v + 1];
    // cA/cB = b_l + lin_r(x[v]) : constant part of m per feature
    float cA = fmaf(xv0, W_r1[f0], fmaf(xv1, W_r1[128 + f0], b_r1[f0])) + b_l1[f0];
    float cB = fmaf(xv0, W_r1[f1], fmaf(xv1, W_r1[128 + f1], b_r1[f1])) + b_l1[f1];

    float lh = 0.f, px0 = 0.f, px1 = 0.f;
    int rs = rowp[v], re = rowp[v + 1];
    bool b0 = (lane & 1) != 0, b1 = (lane & 2) != 0;

    int cs = rs;
#define E1(K, R) \
    float s##K; { \
        float m0 = fmaf(R.x, Wl00, fmaf(R.y, Wl10, fmaf(R.z, We00, fmaf(R.w, We10, cA)))); \
        float m1 = fmaf(R.x, Wl01, fmaf(R.y, Wl11, fmaf(R.z, We01, fmaf(R.w, We11, cB)))); \
        s##K = quadsum(fmaf(fmaxf(m0, 0.2f * m0), a0, fmaxf(m1, 0.2f * m1) * a1)); \
    }
    for (; cs + 4 <= re; cs += 4) {
        float4 r0 = col_rec[cs + 0];
        float4 r1 = col_rec[cs + 1];
        float4 r2 = col_rec[cs + 2];
        float4 r3 = col_rec[cs + 3];
        E1(0, r0) E1(1, r1) E1(2, r2) E1(3, r3)
        float sel01 = b0 ? s1 : s0;
        float sel23 = b0 ? s3 : s2;
        float smy = b1 ? sel23 : sel01;     // lane's own edge score (k = lane&3)
        float p = __expf(smy);
        float p0 = dppf<0x00>(p), p1 = dppf<0x55>(p), p2 = dppf<0xAA>(p), p3 = dppf<0xFF>(p);
        lh += (p0 + p1) + (p2 + p3);
        px0 = fmaf(p0, r0.x, px0); px0 = fmaf(p1, r1.x, px0);
        px0 = fmaf(p2, r2.x, px0); px0 = fmaf(p3, r3.x, px0);
        px1 = fmaf(p0, r0.y, px1); px1 = fmaf(p1, r1.y, px1);
        px1 = fmaf(p2, r2.y, px1); px1 = fmaf(p3, r3.y, px1);
    }
#undef E1
    for (; cs < re; ++cs) {                 // tail (<=3 edges); s quad-uniform, no bcast
        float4 r = col_rec[cs];
        float m0 = fmaf(r.x, Wl00, fmaf(r.y, Wl10, fmaf(r.z, We00, fmaf(r.w, We10, cA))));
        float m1 = fmaf(r.x, Wl01, fmaf(r.y, Wl11, fmaf(r.z, We01, fmaf(r.w, We11, cB))));
        float s = quadsum(fmaf(fmaxf(m0, 0.2f * m0), a0, fmaxf(m1, 0.2f * m1) * a1));
        float p = __expf(s);
        lh += p;
        px0 = fmaf(p, r.x, px0);
        px1 = fmaf(p, r.y, px1);
    }

    float inv = (re > rs) ? 1.f / lh : 0.f;
    if ((lane & 3) == 0)
        qbuf[(size_t)v * 16 + (lane >> 2)] = make_float2(px0 * inv, px1 * inv);
    if (lane == 0) flags[v] = (re > rs) ? 1 : 0;
}

// ---------------- Layer 2 node transforms: register-tiled LDS GEMM ----------------
// hpost reconstructed on-the-fly from q: h = elu(q0*Wl0[f] + q1*Wl1[f] + flag*bl[f] + bias[f])

struct XF2Shared {
    float4 hs[64 * 32];
    float4 ws[128 * 16];
};

__device__ __forceinline__ void xf2_pass(XF2Shared& sm,
                                         const float* __restrict__ W,
                                         const float* __restrict__ b,
                                         float* __restrict__ out,
                                         int v0, int n, int t) {
    __syncthreads();
    {
        const float4* wsrc = (const float4*)W;
#pragma unroll
        for (int i = 0; i < 8; ++i) sm.ws[t + 256 * i] = wsrc[t + 256 * i];
    }
    __syncthreads();

    int lane = t & 63, w = t >> 6;
    int fg = lane & 3, ng = lane >> 2;
    int fq = 4 * w + fg;
    int hsw = ng & 7;

    float acc[4][4];
#pragma unroll
    for (int i = 0; i < 4; ++i)
#pragma unroll
        for (int c = 0; c < 4; ++c) acc[i][c] = 0.f;

    for (int kq = 0; kq < 32; ++kq) {
        float4 w0 = sm.ws[(4 * kq + 0) * 16 + fq];
        float4 w1 = sm.ws[(4 * kq + 1) * 16 + fq];
        float4 w2 = sm.ws[(4 * kq + 2) * 16 + fq];
        float4 w3 = sm.ws[(4 * kq + 3) * 16 + fq];
        int ks = kq ^ hsw;
        float4 h0 = sm.hs[(4 * ng + 0) * 32 + ks];
        float4 h1 = sm.hs[(4 * ng + 1) * 32 + ks];
        float4 h2 = sm.hs[(4 * ng + 2) * 32 + ks];
        float4 h3 = sm.hs[(4 * ng + 3) * 32 + ks];
#pragma unroll
        for (int i = 0; i < 4; ++i) {
            float4 h = (i == 0) ? h0 : (i == 1) ? h1 : (i == 2) ? h2 : h3;
            acc[i][0] += h.x * w0.x; acc[i][1] += h.x * w0.y; acc[i][2] += h.x * w0.z; acc[i][3] += h.x * w0.w;
            acc[i][0] += h.y * w1.x; acc[i][1] += h.y * w1.y; acc[i][2] += h.y * w1.z; acc[i][3] += h.y * w1.w;
            acc[i][0] += h.z * w2.x; acc[i][1] += h.z * w2.y; acc[i][2] += h.z * w2.z; acc[i][3] += h.z * w2.w;
            acc[i][0] += h.w * w3.x; acc[i][1] += h.w * w3.y; acc[i][2] += h.w * w3.z; acc[i][3] += h.w * w3.w;
        }
    }

    float4 bf = ((const float4*)b)[fq];
#pragma unroll
    for (int i = 0; i < 4; ++i) {
        int node = v0 + 4 * ng + i;
        if (node < n) {
            float4 r = make_float4(acc[i][0] + bf.x, acc[i][1] + bf.y,
                                   acc[i][2] + bf.z, acc[i][3] + bf.w);
            *(float4*)(out + (size_t)node * 64 + 4 * fq) = r;
        }
    }
}

__device__ __forceinline__ float elu1(float v) {
    return (v > 0.f) ? v : (__expf(v) - 1.f);
}

__global__ __launch_bounds__(256) void k_transform2(
    const float2* __restrict__ qbuf, const int* __restrict__ flags,
    const float* __restrict__ W_l1, const float* __restrict__ b_l1,
    const float* __restrict__ bias1,
    const float* __restrict__ W_l2, const float* __restrict__ b_l2,
    const float* __restrict__ W_r2, const float* __restrict__ b_r2,
    float* __restrict__ xl2, float* __restrict__ xr2, int n)
{
    __shared__ XF2Shared sm;
    int t = threadIdx.x;
    int v0 = blockIdx.x * 64;
    {
        int node = t >> 2, sub = t & 3;
        int sw = (node >> 2) & 7;
        int gn = v0 + node;
        bool valid = gn < n;
        int fl = valid ? flags[gn] : 0;
        const float4* wl0 = (const float4*)W_l1;           // row 0
        const float4* wl1 = (const float4*)(W_l1 + 128);   // row 1
        const float4* blp = (const float4*)b_l1;
        const float4* bip = (const float4*)bias1;
        float flf = (float)fl;
#pragma unroll
        for (int i = 0; i < 8; ++i) {
            int kq = sub + 4 * i;
            float2 q = valid ? qbuf[(size_t)gn * 16 + (kq >> 1)] : make_float2(0.f, 0.f);
            float4 w0 = wl0[kq], w1 = wl1[kq];
            float4 bl = blp[kq], bi = bip[kq];
            float4 val;
            val.x = elu1(fmaf(q.x, w0.x, fmaf(q.y, w1.x, fmaf(flf, bl.x, bi.x))));
            val.y = elu1(fmaf(q.x, w0.y, fmaf(q.y, w1.y, fmaf(flf, bl.y, bi.y))));
            val.z = elu1(fmaf(q.x, w0.z, fmaf(q.y, w1.z, fmaf(flf, bl.z, bi.z))));
            val.w = elu1(fmaf(q.x, w0.w, fmaf(q.y, w1.w, fmaf(flf, bl.w, bi.w))));
            if (!valid) val = make_float4(0.f, 0.f, 0.f, 0.f);
            sm.hs[node * 32 + (kq ^ sw)] = val;
        }
    }
    xf2_pass(sm, W_l2, b_l2, xl2, v0, n, t);
    xf2_pass(sm, W_r2, b_r2, xr2, v0, n, t);
}

// ---------------- Layer 2 aggregation: no-max softmax ----------------
// wave per node, lane = feature; head = lane>>4 (16-lane groups)

__global__ __launch_bounds__(256) void k_agg2(
    const float* __restrict__ xl2,
    const float* __restrict__ xr2,
    const int* __restrict__ rowp,
    const int* __restrict__ col_src,
    const float4* __restrict__ col_rec,
    const float* __restrict__ W_e2,
    const float* __restrict__ att2,
    const float* __restrict__ bias2,
    float* __restrict__ h2,
    int n)
{
    int wid = (blockIdx.x * blockDim.x + threadIdx.x) >> 6;
    if (wid >= n) return;
    int v = __builtin_amdgcn_readfirstlane(wid);
    int lane = threadIdx.x & 63;
    float We0 = W_e2[lane], We1 = W_e2[64 + lane];
    float a = att2[lane];
    float xr = xr2[(size_t)v * 64 + lane];
    float lh = 0.f, acc = 0.f;
    int rs = rowp[v], re = rowp[v + 1];
    const float2* eap = (const float2*)col_rec;   // {ea0,ea1} at odd float2 slots
    bool b0 = (lane & 1) != 0, b1 = (lane & 2) != 0;

    int cs = rs;
#define E2(K, EV, XL) \
    float s##K; { \
        float m = fmaf(EV.x, We0, fmaf(EV.y, We1, XL + xr)); \
        s##K = sum16(fmaxf(m, 0.2f * m) * a); \
    }
    for (; cs + 4 <= re; cs += 4) {
        int u0 = col_src[cs], u1 = col_src[cs + 1], u2 = col_src[cs + 2], u3 = col_src[cs + 3];
        float2 e0 = eap[2 * cs + 1], e1 = eap[2 * cs + 3];
        float2 e2 = eap[2 * cs + 5], e3 = eap[2 * cs + 7];
        float xl0 = xl2[(size_t)u0 * 64 + lane];
        float xl1 = xl2[(size_t)u1 * 64 + lane];
        float xl2_ = xl2[(size_t)u2 * 64 + lane];
        float xl3 = xl2[(size_t)u3 * 64 + lane];
        E2(0, e0, xl0) E2(1, e1, xl1) E2(2, e2, xl2_) E2(3, e3, xl3)
        float sel01 = b0 ? s1 : s0;
        float sel23 = b0 ? s3 : s2;
        float smy = b1 ? sel23 : sel01;
        float p = __expf(smy);
        float p0 = dppf<0x00>(p), p1 = dppf<0x55>(p), p2 = dppf<0xAA>(p), p3 = dppf<0xFF>(p);
        lh += (p0 + p1) + (p2 + p3);
        acc = fmaf(p0, xl0, acc); acc = fmaf(p1, xl1, acc);
        acc = fmaf(p2, xl2_, acc); acc = fmaf(p3, xl3, acc);
    }
#undef E2
    for (; cs < re; ++cs) {
        int u = col_src[cs];
        float2 ev = eap[2 * cs + 1];
        float xl = xl2[(size_t)u * 64 + lane];
        float m = fmaf(ev.x, We0, fmaf(ev.y, We1, xl + xr));
        float s = sum16(fmaxf(m, 0.2f * m) * a);
        float p = __expf(s);
        lh += p;
        acc = fmaf(p, xl, acc);
    }
    float r = (re > rs) ? acc / lh : 0.f;
    h2[(size_t)v * 64 + lane] = r + bias2[lane];
}

// ---------------- Mean pool over graphs (batch sorted: segmented reduce) ----------------

__global__ __launch_bounds__(256) void k_pool2(const float* __restrict__ h2,
                                               const int* __restrict__ batch,
                                               float* __restrict__ sums, float* __restrict__ cnt,
                                               int n, int chunk) {
    int w = (blockIdx.x * blockDim.x + threadIdx.x) >> 6;
    int lane = threadIdx.x & 63;
    int start = w * chunk;
    if (start >= n) return;
    int end = min(n, start + chunk);
    int g = batch[start];
    float acc = 0.f;
    int c = 0;
    for (int v = start; v < end; ++v) {
        int bg = batch[v];
        if (bg != g) {
            atomicAdd(&sums[g * 64 + lane], acc);
            if (lane == 0) atomicAdd(&cnt[g], (float)c);
            acc = 0.f; c = 0; g = bg;
        }
        acc += h2[(size_t)v * 64 + lane];
        ++c;
    }
    atomicAdd(&sums[g * 64 + lane], acc);
    if (lane == 0) atomicAdd(&cnt[g], (float)c);
}

__global__ void k_final(const float* __restrict__ sums, const float* __restrict__ cnt,
                        float* __restrict__ out, int g) {
    int i = blockIdx.x * blockDim.x + threadIdx.x;
    if (i < g * 64) out[i] = sums[i] / fmaxf(cnt[i >> 6], 1.f);
}

// ---------------- launch ----------------

extern "C" void kernel_launch(void* const* d_in, const int* in_sizes, int n_in,
                              void* d_out, int out_size, void* d_ws, size_t ws_size,
                              hipStream_t stream) {
    const float* x     = (const float*)d_in[0];
    const float* ea    = (const float*)d_in[1];
    const float* W_l1  = (const float*)d_in[2];
    const float* b_l1  = (const float*)d_in[3];
    const float* W_r1  = (const float*)d_in[4];
    const float* b_r1  = (const float*)d_in[5];
    const float* W_e1  = (const float*)d_in[6];
    const float* att1  = (const float*)d_in[7];
    const float* bias1 = (const float*)d_in[8];
    const float* W_l2  = (const float*)d_in[9];
    const float* b_l2  = (const float*)d_in[10];
    const float* W_r2  = (const float*)d_in[11];
    const float* b_r2  = (const float*)d_in[12];
    const float* W_e2  = (const float*)d_in[13];
    const float* att2  = (const float*)d_in[14];
    const float* bias2 = (const float*)d_in[15];
    const int* eidx    = (const int*)d_in[16];
    const int* batch   = (const int*)d_in[17];

    int n = in_sizes[0] / 2;     // 50000
    int e = in_sizes[16] / 2;    // 800000
    int g = out_size / 64;       // 64
    const int* srcI = eidx;
    const int* tgtI = eidx + e;
    int nb = (n + 127) / 128;    // 391 buckets (128 nodes each)
    int ntot = nb * NBLK;        // cell table size
    int nb2 = (ntot + 255) / 256;
    int chunk = (e + NBLK - 1) / NBLK;

    char* w = (char*)d_ws;
    size_t off = 0;
    auto take = [&](size_t bytes) -> char* {
        size_t a = (off + 255) & ~(size_t)255;
        off = a + bytes;
        return w + a;
    };
    // region1: brec (sort phase) then h2 (agg2 output)
    char*   reg1    = take((size_t)e * 16);             // 12.8 MB
    float4* brec    = (float4*)reg1;
    float*  h2      = (float*)reg1;
    // region2: bmeta (sort phase) then xl2 (transform2..agg2)
    char*   reg2    = take((size_t)n * 64 * 4);         // 12.8 MB >= e*4
    int*    bmeta   = (int*)reg2;
    float*  xl2     = (float*)reg2;

    float*  xr2     = (float*)take((size_t)n * 64 * 4);
    float4* col_rec = (float4*)take((size_t)e * 16);
    int*    col_src = (int*)take((size_t)e * 4);
    int*    rowp    = (int*)take((size_t)(n + 1) * 4);
    float2* qbuf    = (float2*)take((size_t)n * 16 * 8);
    int*    flags   = (int*)take((size_t)n * 4);
    int*    gh      = (int*)take((size_t)ntot * 4);
    int*    gexcl   = (int*)take((size_t)(ntot + 1) * 4);
    int*    gbsum   = (int*)take((size_t)nb2 * 4);
    int*    gboff   = (int*)take((size_t)nb2 * 4);
    float*  sums    = (float*)take((size_t)g * 64 * 4);
    float*  cnt     = (float*)take((size_t)g * 4);

    k_init<<<(g * 64 + 255) / 256, 256, 0, stream>>>(sums, cnt, g);

    // dense two-pass counting sort by (bucket, block)
    k_hist<<<NBLK, 256, 0, stream>>>(tgtI, gh, e, chunk, nb);
    k_scanA<<<nb2, 256, 0, stream>>>(gh, gexcl, gbsum, ntot);
    k_scanB<<<1, 256, 0, stream>>>(gbsum, gboff, nb2);
    k_binplace<<<NBLK, 256, 0, stream>>>(srcI, tgtI, ea, x, gexcl, gboff, brec, bmeta,
                                         e, chunk, nb);
    k_place2<<<nb, 256, 0, stream>>>(gexcl, gboff, bmeta, brec, col_rec, col_src, rowp,
                                     n, ntot, e);

    int nwaveblocks = (n * 64 + 255) / 256;
    k_agg1<<<nwaveblocks, 256, 0, stream>>>(x, rowp, col_rec,
                                            W_l1, b_l1, W_r1, b_r1, W_e1, att1,
                                            qbuf, flags, n);
    int ntiles = (n + 63) / 64;
    k_transform2<<<ntiles, 256, 0, stream>>>(qbuf, flags, W_l1, b_l1, bias1,
                                             W_l2, b_l2, W_r2, b_r2, xl2, xr2, n);
    k_agg2<<<nwaveblocks, 256, 0, stream>>>(xl2, xr2, rowp, col_src, col_rec,
                                            W_e2, att2, bias2, h2, n);

    int pool_waves = 1024;
    int pool_chunk = (n + pool_waves - 1) / pool_waves;
    k_pool2<<<pool_waves / 4, 256, 0, stream>>>(h2, batch, sums, cnt, n, pool_chunk);
    k_final<<<(g * 64 + 255) / 256, 256, 0, stream>>>(sums, cnt, (float*)d_out, g);
}

// Round 14
// 179.958 us; speedup vs baseline: 1.0054x; 1.0054x over previous
//
#include <hip/hip_runtime.h>
#include <math.h>

#define NBLK 512     // bucketing blocks (each owns a contiguous edge chunk)
#define BSHIFT 8     // 256 nodes per bucket
#define BMASK 255

// ---------------- DPP helpers (full-rate VALU cross-lane, no LDS) ----------------

template<int CTRL>
__device__ __forceinline__ float dppf(float x) {
    return __int_as_float(__builtin_amdgcn_update_dpp(
        0, __float_as_int(x), CTRL, 0xF, 0xF, true));
}
// sum over 4-lane quad (lanes end with identical value)
__device__ __forceinline__ float quadsum(float x) {
    x += dppf<0xB1>(x);   // quad_perm xor 1
    x += dppf<0x4E>(x);   // quad_perm xor 2
    return x;
}
// sum over 16-lane group
__device__ __forceinline__ float sum16(float x) {
    x += dppf<0xB1>(x);
    x += dppf<0x4E>(x);
    x += dppf<0x141>(x);  // row_half_mirror
    x += dppf<0x140>(x);  // row_mirror
    return x;
}

// ---------------- Pass 1: per-(bucket,block) histogram, LDS only ----------------
// block 0 also zero-fills the pool accumulators (replaces k_init / memset).

__global__ __launch_bounds__(256) void k_hist(const int* __restrict__ tgt,
                                              int* __restrict__ gh,
                                              float* __restrict__ sums,
                                              float* __restrict__ cnt, int gn,
                                              int e, int chunk, int nbuck) {
    __shared__ int lh[256];
    int tid = threadIdx.x, blk = blockIdx.x;
    if (blk == 0) {
        for (int i = tid; i < gn * 64; i += 256) sums[i] = 0.f;
        for (int i = tid; i < gn; i += 256) cnt[i] = 0.f;
    }
    lh[tid] = 0;
    __syncthreads();
    int lo = blk * chunk, hi = min(lo + chunk, e);
    for (int i = lo + tid; i < hi; i += 256)
        atomicAdd(&lh[tgt[i] >> BSHIFT], 1);
    __syncthreads();
    if (tid < nbuck) gh[tid * NBLK + blk] = lh[tid];
}

// ---------------- scan kernels (cell table; boff folded into consumers) ----------------

__global__ __launch_bounds__(256) void k_scanA(const int* __restrict__ deg,
                                               int* __restrict__ excl,
                                               int* __restrict__ bsum, int n) {
    int i = blockIdx.x * 256 + threadIdx.x;
    int lane = threadIdx.x & 63, wv = threadIdx.x >> 6;
    int v = (i < n) ? deg[i] : 0;
    int incl = v;
#pragma unroll
    for (int off = 1; off < 64; off <<= 1) {
        int t = __shfl_up(incl, off);
        if (lane >= off) incl += t;
    }
    __shared__ int ws[4];
    if (lane == 63) ws[wv] = incl;
    __syncthreads();
    int prefix = 0;
    for (int k = 0; k < wv; ++k) prefix += ws[k];
    if (i < n) excl[i] = prefix + incl - v;
    if (threadIdx.x == 255) bsum[blockIdx.x] = prefix + incl;
}

__global__ __launch_bounds__(256) void k_scanB(const int* __restrict__ bsum, int* __restrict__ boff,
                                               int nb) {
    __shared__ int ws[4];
    __shared__ int carry_s;
    int lane = threadIdx.x & 63, wv = threadIdx.x >> 6;
    if (threadIdx.x == 0) carry_s = 0;
    __syncthreads();
    for (int base = 0; base < nb; base += 256) {
        int i = base + threadIdx.x;
        int v = (i < nb) ? bsum[i] : 0;
        int incl = v;
#pragma unroll
        for (int off = 1; off < 64; off <<= 1) {
            int t = __shfl_up(incl, off);
            if (lane >= off) incl += t;
        }
        if (lane == 63) ws[wv] = incl;
        __syncthreads();
        int prefix = carry_s;
        for (int k = 0; k < wv; ++k) prefix += ws[k];
        if (i < nb) boff[i] = prefix + incl - v;
        __syncthreads();
        if (threadIdx.x == 255) carry_s = prefix + incl;
        __syncthreads();
    }
}

// ---------------- Pass 2: block-dense bucket placement (no global atomics) ----------------

__global__ __launch_bounds__(256) void k_binplace(const int* __restrict__ src,
                                                  const int* __restrict__ tgt,
                                                  const float* __restrict__ ea,
                                                  const float* __restrict__ x,
                                                  const int* __restrict__ gexcl,
                                                  const int* __restrict__ gboff,
                                                  float4* __restrict__ brec,
                                                  int* __restrict__ bmeta,
                                                  int e, int chunk, int nbuck) {
    __shared__ int loff[256];
    int tid = threadIdx.x, blk = blockIdx.x;
    if (tid < nbuck) {
        int cell = tid * NBLK + blk;
        loff[tid] = gexcl[cell] + gboff[cell >> 8];
    }
    __syncthreads();
    int lo = blk * chunk, hi = min(lo + chunk, e);
    for (int i = lo + tid; i < hi; i += 256) {
        int t = tgt[i], s = src[i];
        float2 ev = ((const float2*)ea)[i];
        float2 xv = *(const float2*)(x + 2 * (size_t)s);
        int dst = atomicAdd(&loff[t >> BSHIFT], 1);
        brec[dst] = make_float4(xv.x, xv.y, ev.x, ev.y);     // {x[src], ea}
        bmeta[dst] = (s & 0xFFFF) | ((t & BMASK) << 16);     // src16 | tgt_local8
    }
}

// ---------------- fused: per-bucket degree hist + scan + rowp + CSR placement ----------------

__global__ __launch_bounds__(256) void k_place2(const int* __restrict__ gexcl,
                                                const int* __restrict__ gboff,
                                                const int* __restrict__ bmeta,
                                                const float4* __restrict__ brec,
                                                float4* __restrict__ col_rec,
                                                unsigned short* __restrict__ col_src,
                                                int* __restrict__ rowp,
                                                int n, int ntot, int e) {
    __shared__ int hist[256];
    __shared__ int pos[256];
    __shared__ int ws[4];
    int b = blockIdx.x, tid = threadIdx.x;
    int clo = b * NBLK, chi = clo + NBLK;
    int lo = gexcl[clo] + gboff[clo >> 8];
    int hi = (chi >= ntot) ? e : (gexcl[chi] + gboff[chi >> 8]);
    hist[tid] = 0;
    __syncthreads();
    for (int i = lo + tid; i < hi; i += 256)
        atomicAdd(&hist[(bmeta[i] >> 16) & BMASK], 1);
    __syncthreads();
    int lane = tid & 63, wv = tid >> 6;
    int v = hist[tid];
    int incl = v;
#pragma unroll
    for (int off = 1; off < 64; off <<= 1) {
        int t = __shfl_up(incl, off);
        if (lane >= off) incl += t;
    }
    if (lane == 63) ws[wv] = incl;
    __syncthreads();
    int prefix = 0;
    for (int k = 0; k < wv; ++k) prefix += ws[k];
    int rp = lo + prefix + incl - v;
    int node = b * 256 + tid;
    if (node <= n) rowp[node] = rp;
    if (b == (int)gridDim.x - 1 && tid == 255) rowp[n] = hi;
    pos[tid] = rp;
    __syncthreads();
    for (int i = lo + tid; i < hi; i += 256) {
        int m = bmeta[i];
        float4 r = brec[i];
        int slot = atomicAdd(&pos[(m >> 16) & BMASK], 1);
        col_rec[slot] = r;
        col_src[slot] = (unsigned short)(m & 0xFFFF);
    }
}

// ---------------- Layer 1: linearized no-max softmax aggregation ----------------
// wave per node; lane l owns features 2l,2l+1; head = l>>2 (4-lane quad groups).
// Output per node: 16 head-pairs q=(px0,px1)/lh (6.4MB) + deg>0 flag. hpost is
// reconstructed on the fly in k_transform2 (saves the 25.6MB hpost round trip).

__global__ __launch_bounds__(256) void k_agg1(
    const float* __restrict__ x,
    const int* __restrict__ rowp,
    const float4* __restrict__ col_rec,
    const float* __restrict__ W_l1, const float* __restrict__ b_l1,
    const float* __restrict__ W_r1, const float* __restrict__ b_r1,
    const float* __restrict__ W_e1,
    const float* __restrict__ att1,
    float2* __restrict__ qbuf,       // [n*16]
    int* __restrict__ flags,         // [n]
    int n)
{
    int wid = (blockIdx.x * blockDim.x + threadIdx.x) >> 6;
    if (wid >= n) return;
    int v = __builtin_amdgcn_readfirstlane(wid);
    int lane = threadIdx.x & 63;
    int f0 = 2 * lane, f1 = 2 * lane + 1;

    float Wl00 = W_l1[f0], Wl10 = W_l1[128 + f0];
    float Wl01 = W_l1[f1], Wl11 = W_l1[128 + f1];
    float We00 = W_e1[f0], We10 = W_e1[128 + f0];
    float We01 = W_e1[f1], We11 = W_e1[128 + f1];
    float a0 = att1[f0], a1 = att1[f1];

    float xv0 = x[2 * v], xv1 = x[2 * v + 1];
    // cA/cB = b_l + lin_r(x[v]) : constant part of m per feature
    float cA = fmaf(xv0, W_r1[f0], fmaf(xv1, W_r1[128 + f0], b_r1[f0])) + b_l1[f0];
    float cB = fmaf(xv0, W_r1[f1], fmaf(xv1, W_r1[128 + f1], b_r1[f1])) + b_l1[f1];

    float lh = 0.f, px0 = 0.f, px1 = 0.f;
    int rs = rowp[v], re = rowp[v + 1];
    bool b0 = (lane & 1) != 0, b1 = (lane & 2) != 0;

    int cs = rs;
#define E1(K, R) \
    float s##K; { \
        float m0 = fmaf(R.x, Wl00, fmaf(R.y, Wl10, fmaf(R.z, We00, fmaf(R.w, We10, cA)))); \
        float m1 = fmaf(R.x, Wl01, fmaf(R.y, Wl11, fmaf(R.z, We01, fmaf(R.w, We11, cB)))); \
        s##K = quadsum(fmaf(fmaxf(m0, 0.2f * m0), a0, fmaxf(m1, 0.2f * m1) * a1)); \
    }
    for (; cs + 4 <= re; cs += 4) {
        float4 r0 = col_rec[cs + 0];
        float4 r1 = col_rec[cs + 1];
        float4 r2 = col_rec[cs + 2];
        float4 r3 = col_rec[cs + 3];
        E1(0, r0) E1(1, r1) E1(2, r2) E1(3, r3)
        float sel01 = b0 ? s1 : s0;
        float sel23 = b0 ? s3 : s2;
        float smy = b1 ? sel23 : sel01;     // lane's own edge score (k = lane&3)
        float p = __expf(smy);
        float p0 = dppf<0x00>(p), p1 = dppf<0x55>(p), p2 = dppf<0xAA>(p), p3 = dppf<0xFF>(p);
        lh += (p0 + p1) + (p2 + p3);
        px0 = fmaf(p0, r0.x, px0); px0 = fmaf(p1, r1.x, px0);
        px0 = fmaf(p2, r2.x, px0); px0 = fmaf(p3, r3.x, px0);
        px1 = fmaf(p0, r0.y, px1); px1 = fmaf(p1, r1.y, px1);
        px1 = fmaf(p2, r2.y, px1); px1 = fmaf(p3, r3.y, px1);
    }
#undef E1
    for (; cs < re; ++cs) {                 // tail (<=3 edges); s quad-uniform, no bcast
        float4 r = col_rec[cs];
        float m0 = fmaf(r.x, Wl00, fmaf(r.y, Wl10, fmaf(r.z, We00, fmaf(r.w, We10, cA))));
        float m1 = fmaf(r.x, Wl01, fmaf(r.y, Wl11, fmaf(r.z, We01, fmaf(r.w, We11, cB))));
        float s = quadsum(fmaf(fmaxf(m0, 0.2f * m0), a0, fmaxf(m1, 0.2f * m1) * a1));
        float p = __expf(s);
        lh += p;
        px0 = fmaf(p, r.x, px0);
        px1 = fmaf(p, r.y, px1);
    }

    float inv = (re > rs) ? 1.f / lh : 0.f;
    if ((lane & 3) == 0)
        qbuf[(size_t)v * 16 + (lane >> 2)] = make_float2(px0 * inv, px1 * inv);
    if (lane == 0) flags[v] = (re > rs) ? 1 : 0;
}

// ---------------- Layer 2 node transforms: register-tiled LDS GEMM ----------------
// hpost reconstructed on-the-fly from q: h = elu(q0*Wl0[f] + q1*Wl1[f] + flag*bl[f] + bias[f])

struct XF2Shared {
    float4 hs[64 * 32];
    float4 ws[128 * 16];
};

__device__ __forceinline__ void xf2_pass(XF2Shared& sm,
                                         const float* __restrict__ W,
                                         const float* __restrict__ b,
                                         float* __restrict__ out,
                                         int v0, int n, int t) {
    __syncthreads();
    {
        const float4* wsrc = (const float4*)W;
#pragma unroll
        for (int i = 0; i < 8; ++i) sm.ws[t + 256 * i] = wsrc[t + 256 * i];
    }
    __syncthreads();

    int lane = t & 63, w = t >> 6;
    int fg = lane & 3, ng = lane >> 2;
    int fq = 4 * w + fg;
    int hsw = ng & 7;

    float acc[4][4];
#pragma unroll
    for (int i = 0; i < 4; ++i)
#pragma unroll
        for (int c = 0; c < 4; ++c) acc[i][c] = 0.f;

    for (int kq = 0; kq < 32; ++kq) {
        float4 w0 = sm.ws[(4 * kq + 0) * 16 + fq];
        float4 w1 = sm.ws[(4 * kq + 1) * 16 + fq];
        float4 w2 = sm.ws[(4 * kq + 2) * 16 + fq];
        float4 w3 = sm.ws[(4 * kq + 3) * 16 + fq];
        int ks = kq ^ hsw;
        float4 h0 = sm.hs[(4 * ng + 0) * 32 + ks];
        float4 h1 = sm.hs[(4 * ng + 1) * 32 + ks];
        float4 h2 = sm.hs[(4 * ng + 2) * 32 + ks];
        float4 h3 = sm.hs[(4 * ng + 3) * 32 + ks];
#pragma unroll
        for (int i = 0; i < 4; ++i) {
            float4 h = (i == 0) ? h0 : (i == 1) ? h1 : (i == 2) ? h2 : h3;
            acc[i][0] += h.x * w0.x; acc[i][1] += h.x * w0.y; acc[i][2] += h.x * w0.z; acc[i][3] += h.x * w0.w;
            acc[i][0] += h.y * w1.x; acc[i][1] += h.y * w1.y; acc[i][2] += h.y * w1.z; acc[i][3] += h.y * w1.w;
            acc[i][0] += h.z * w2.x; acc[i][1] += h.z * w2.y; acc[i][2] += h.z * w2.z; acc[i][3] += h.z * w2.w;
            acc[i][0] += h.w * w3.x; acc[i][1] += h.w * w3.y; acc[i][2] += h.w * w3.z; acc[i][3] += h.w * w3.w;
        }
    }

    float4 bf = ((const float4*)b)[fq];
#pragma unroll
    for (int i = 0; i < 4; ++i) {
        int node = v0 + 4 * ng + i;
        if (node < n) {
            float4 r = make_float4(acc[i][0] + bf.x, acc[i][1] + bf.y,
                                   acc[i][2] + bf.z, acc[i][3] + bf.w);
            *(float4*)(out + (size_t)node * 64 + 4 * fq) = r;
        }
    }
}

__device__ __forceinline__ float elu1(float v) {
    return (v > 0.f) ? v : (__expf(v) - 1.f);
}

__global__ __launch_bounds__(256) void k_transform2(
    const float2* __restrict__ qbuf, const int* __restrict__ flags,
    const float* __restrict__ W_l1, const float* __restrict__ b_l1,
    const float* __restrict__ bias1,
    const float* __restrict__ W_l2, const float* __restrict__ b_l2,
    const float* __restrict__ W_r2, const float* __restrict__ b_r2,
    float* __restrict__ xl2, float* __restrict__ xr2, int n)
{
    __shared__ XF2Shared sm;
    int t = threadIdx.x;
    int v0 = blockIdx.x * 64;
    {
        int node = t >> 2, sub = t & 3;
        int sw = (node >> 2) & 7;
        int gn = v0 + node;
        bool valid = gn < n;
        int fl = valid ? flags[gn] : 0;
        const float4* wl0 = (const float4*)W_l1;           // row 0
        const float4* wl1 = (const float4*)(W_l1 + 128);   // row 1
        const float4* blp = (const float4*)b_l1;
        const float4* bip = (const float4*)bias1;
        float flf = (float)fl;
#pragma unroll
        for (int i = 0; i < 8; ++i) {
            int kq = sub + 4 * i;
            float2 q = valid ? qbuf[(size_t)gn * 16 + (kq >> 1)] : make_float2(0.f, 0.f);
            float4 w0 = wl0[kq], w1 = wl1[kq];
            float4 bl = blp[kq], bi = bip[kq];
            float4 val;
            val.x = elu1(fmaf(q.x, w0.x, fmaf(q.y, w1.x, fmaf(flf, bl.x, bi.x))));
            val.y = elu1(fmaf(q.x, w0.y, fmaf(q.y, w1.y, fmaf(flf, bl.y, bi.y))));
            val.z = elu1(fmaf(q.x, w0.z, fmaf(q.y, w1.z, fmaf(flf, bl.z, bi.z))));
            val.w = elu1(fmaf(q.x, w0.w, fmaf(q.y, w1.w, fmaf(flf, bl.w, bi.w))));
            if (!valid) val = make_float4(0.f, 0.f, 0.f, 0.f);
            sm.hs[node * 32 + (kq ^ sw)] = val;
        }
    }
    xf2_pass(sm, W_l2, b_l2, xl2, v0, n, t);
    xf2_pass(sm, W_r2, b_r2, xr2, v0, n, t);
}

// ---------------- Layer 2 aggregation: no-max softmax ----------------
// wave per node, lane = feature; head = lane>>4 (16-lane groups)

__global__ __launch_bounds__(256) void k_agg2(
    const float* __restrict__ xl2,
    const float* __restrict__ xr2,
    const int* __restrict__ rowp,
    const unsigned short* __restrict__ col_src,
    const float4* __restrict__ col_rec,
    const float* __restrict__ W_e2,
    const float* __restrict__ att2,
    const float* __restrict__ bias2,
    float* __restrict__ h2,
    int n)
{
    int wid = (blockIdx.x * blockDim.x + threadIdx.x) >> 6;
    if (wid >= n) return;
    int v = __builtin_amdgcn_readfirstlane(wid);
    int lane = threadIdx.x & 63;
    float We0 = W_e2[lane], We1 = W_e2[64 + lane];
    float a = att2[lane];
    float xr = xr2[(size_t)v * 64 + lane];
    float lh = 0.f, acc = 0.f;
    int rs = rowp[v], re = rowp[v + 1];
    const float2* eap = (const float2*)col_rec;   // {ea0,ea1} at odd float2 slots
    bool b0 = (lane & 1) != 0, b1 = (lane & 2) != 0;

    int cs = rs;
#define E2(K, EV, XL) \
    float s##K; { \
        float m = fmaf(EV.x, We0, fmaf(EV.y, We1, XL + xr)); \
        s##K = sum16(fmaxf(m, 0.2f * m) * a); \
    }
    for (; cs + 4 <= re; cs += 4) {
        int u0 = col_src[cs], u1 = col_src[cs + 1], u2 = col_src[cs + 2], u3 = col_src[cs + 3];
        float2 e0 = eap[2 * cs + 1], e1 = eap[2 * cs + 3];
        float2 e2 = eap[2 * cs + 5], e3 = eap[2 * cs + 7];
        float xl0 = xl2[(size_t)u0 * 64 + lane];
        float xl1 = xl2[(size_t)u1 * 64 + lane];
        float xl2_ = xl2[(size_t)u2 * 64 + lane];
        float xl3 = xl2[(size_t)u3 * 64 + lane];
        E2(0, e0, xl0) E2(1, e1, xl1) E2(2, e2, xl2_) E2(3, e3, xl3)
        float sel01 = b0 ? s1 : s0;
        float sel23 = b0 ? s3 : s2;
        float smy = b1 ? sel23 : sel01;
        float p = __expf(smy);
        float p0 = dppf<0x00>(p), p1 = dppf<0x55>(p), p2 = dppf<0xAA>(p), p3 = dppf<0xFF>(p);
        lh += (p0 + p1) + (p2 + p3);
        acc = fmaf(p0, xl0, acc); acc = fmaf(p1, xl1, acc);
        acc = fmaf(p2, xl2_, acc); acc = fmaf(p3, xl3, acc);
    }
#undef E2
    for (; cs < re; ++cs) {
        int u = col_src[cs];
        float2 ev = eap[2 * cs + 1];
        float xl = xl2[(size_t)u * 64 + lane];
        float m = fmaf(ev.x, We0, fmaf(ev.y, We1, xl + xr));
        float s = sum16(fmaxf(m, 0.2f * m) * a);
        float p = __expf(s);
        lh += p;
        acc = fmaf(p, xl, acc);
    }
    float r = (re > rs) ? acc / lh : 0.f;
    h2[(size_t)v * 64 + lane] = r + bias2[lane];
}

// ---------------- Mean pool over graphs (batch sorted: segmented reduce) ----------------

__global__ __launch_bounds__(256) void k_pool2(const float* __restrict__ h2,
                                               const int* __restrict__ batch,
                                               float* __restrict__ sums, float* __restrict__ cnt,
                                               int n, int chunk) {
    int w = (blockIdx.x * blockDim.x + threadIdx.x) >> 6;
    int lane = threadIdx.x & 63;
    int start = w * chunk;
    if (start >= n) return;
    int end = min(n, start + chunk);
    int g = batch[start];
    float acc = 0.f;
    int c = 0;
    for (int v = start; v < end; ++v) {
        int bg = batch[v];
        if (bg != g) {
            atomicAdd(&sums[g * 64 + lane], acc);
            if (lane == 0) atomicAdd(&cnt[g], (float)c);
            acc = 0.f; c = 0; g = bg;
        }
        acc += h2[(size_t)v * 64 + lane];
        ++c;
    }
    atomicAdd(&sums[g * 64 + lane], acc);
    if (lane == 0) atomicAdd(&cnt[g], (float)c);
}

__global__ void k_final(const float* __restrict__ sums, const float* __restrict__ cnt,
                        float* __restrict__ out, int g) {
    int i = blockIdx.x * blockDim.x + threadIdx.x;
    if (i < g * 64) out[i] = sums[i] / fmaxf(cnt[i >> 6], 1.f);
}

// ---------------- launch ----------------

extern "C" void kernel_launch(void* const* d_in, const int* in_sizes, int n_in,
                              void* d_out, int out_size, void* d_ws, size_t ws_size,
                              hipStream_t stream) {
    const float* x     = (const float*)d_in[0];
    const float* ea    = (const float*)d_in[1];
    const float* W_l1  = (const float*)d_in[2];
    const float* b_l1  = (const float*)d_in[3];
    const float* W_r1  = (const float*)d_in[4];
    const float* b_r1  = (const float*)d_in[5];
    const float* W_e1  = (const float*)d_in[6];
    const float* att1  = (const float*)d_in[7];
    const float* bias1 = (const float*)d_in[8];
    const float* W_l2  = (const float*)d_in[9];
    const float* b_l2  = (const float*)d_in[10];
    const float* W_r2  = (const float*)d_in[11];
    const float* b_r2  = (const float*)d_in[12];
    const float* W_e2  = (const float*)d_in[13];
    const float* att2  = (const float*)d_in[14];
    const float* bias2 = (const float*)d_in[15];
    const int* eidx    = (const int*)d_in[16];
    const int* batch   = (const int*)d_in[17];

    int n = in_sizes[0] / 2;     // 50000
    int e = in_sizes[16] / 2;    // 800000
    int g = out_size / 64;       // 64
    const int* srcI = eidx;
    const int* tgtI = eidx + e;
    int nb = (n + 255) / 256;    // 196 buckets (256 nodes each)
    int ntot = nb * NBLK;        // cell table size
    int nb2 = (ntot + 255) / 256;
    int chunk = (e + NBLK - 1) / NBLK;

    char* w = (char*)d_ws;
    size_t off = 0;
    auto take = [&](size_t bytes) -> char* {
        size_t a = (off + 255) & ~(size_t)255;
        off = a + bytes;
        return w + a;
    };
    // region1: brec (sort phase) then h2 (agg2 output)
    char*   reg1    = take((size_t)e * 16);             // 12.8 MB
    float4* brec    = (float4*)reg1;
    float*  h2      = (float*)reg1;
    // region2: bmeta (sort phase) then xl2 (transform2..agg2)
    char*   reg2    = take((size_t)n * 64 * 4);         // 12.8 MB >= e*4
    int*    bmeta   = (int*)reg2;
    float*  xl2     = (float*)reg2;

    float*  xr2     = (float*)take((size_t)n * 64 * 4);
    float4* col_rec = (float4*)take((size_t)e * 16);
    unsigned short* col_src = (unsigned short*)take((size_t)e * 2);
    int*    rowp    = (int*)take((size_t)(n + 1) * 4);
    float2* qbuf    = (float2*)take((size_t)n * 16 * 8);
    int*    flags   = (int*)take((size_t)n * 4);
    int*    gh      = (int*)take((size_t)ntot * 4);
    int*    gexcl   = (int*)take((size_t)(ntot + 1) * 4);
    int*    gbsum   = (int*)take((size_t)nb2 * 4);
    int*    gboff   = (int*)take((size_t)nb2 * 4);
    float*  sums    = (float*)take((size_t)g * 64 * 4);
    float*  cnt     = (float*)take((size_t)g * 4);

    // dense two-pass counting sort by (bucket, block); k_hist also zero-inits pool accum
    k_hist<<<NBLK, 256, 0, stream>>>(tgtI, gh, sums, cnt, g, e, chunk, nb);
    k_scanA<<<nb2, 256, 0, stream>>>(gh, gexcl, gbsum, ntot);
    k_scanB<<<1, 256, 0, stream>>>(gbsum, gboff, nb2);
    k_binplace<<<NBLK, 256, 0, stream>>>(srcI, tgtI, ea, x, gexcl, gboff, brec, bmeta,
                                         e, chunk, nb);
    k_place2<<<nb, 256, 0, stream>>>(gexcl, gboff, bmeta, brec, col_rec, col_src, rowp,
                                     n, ntot, e);

    int nwaveblocks = (n * 64 + 255) / 256;
    k_agg1<<<nwaveblocks, 256, 0, stream>>>(x, rowp, col_rec,
                                            W_l1, b_l1, W_r1, b_r1, W_e1, att1,
                                            qbuf, flags, n);
    int ntiles = (n + 63) / 64;
    k_transform2<<<ntiles, 256, 0, stream>>>(qbuf, flags, W_l1, b_l1, bias1,
                                             W_l2, b_l2, W_r2, b_r2, xl2, xr2, n);
    k_agg2<<<nwaveblocks, 256, 0, stream>>>(xl2, xr2, rowp, col_src, col_rec,
                                            W_e2, att2, bias2, h2, n);

    int pool_waves = 1024;
    int pool_chunk = (n + pool_waves - 1) / pool_waves;
    k_pool2<<<pool_waves / 4, 256, 0, stream>>>(h2, batch, sums, cnt, n, pool_chunk);
    k_final<<<(g * 64 + 255) / 256, 256, 0, stream>>>(sums, cnt, (float*)d_out, g);
}

// Round 15
// 174.470 us; speedup vs baseline: 1.0370x; 1.0315x over previous
//
#include <hip/hip_runtime.h>
#include <math.h>

#define NBLK 512     // bucketing blocks (each owns a contiguous edge chunk)
#define BSHIFT 8     // 256 nodes per bucket
#define BMASK 255

// ---------------- DPP helpers (full-rate VALU cross-lane, no LDS) ----------------

template<int CTRL>
__device__ __forceinline__ float dppf(float x) {
    return __int_as_float(__builtin_amdgcn_update_dpp(
        0, __float_as_int(x), CTRL, 0xF, 0xF, true));
}
// sum over 4-lane quad (lanes end with identical value)
__device__ __forceinline__ float quadsum(float x) {
    x += dppf<0xB1>(x);   // quad_perm xor 1
    x += dppf<0x4E>(x);   // quad_perm xor 2
    return x;
}
// sum over 16-lane group
__device__ __forceinline__ float sum16(float x) {
    x += dppf<0xB1>(x);
    x += dppf<0x4E>(x);
    x += dppf<0x141>(x);  // row_half_mirror
    x += dppf<0x140>(x);  // row_mirror
    return x;
}

// ---------------- Pass 1: per-(bucket,block) histogram, LDS only ----------------
// block 0 also zero-fills the pool accumulators (replaces k_init / memset).

__global__ __launch_bounds__(256) void k_hist(const int* __restrict__ tgt,
                                              int* __restrict__ gh,
                                              float* __restrict__ sums,
                                              float* __restrict__ cnt, int gn,
                                              int e, int chunk, int nbuck) {
    __shared__ int lh[256];
    int tid = threadIdx.x, blk = blockIdx.x;
    if (blk == 0) {
        for (int i = tid; i < gn * 64; i += 256) sums[i] = 0.f;
        for (int i = tid; i < gn; i += 256) cnt[i] = 0.f;
    }
    lh[tid] = 0;
    __syncthreads();
    int lo = blk * chunk, hi = min(lo + chunk, e);
    for (int i = lo + tid; i < hi; i += 256)
        atomicAdd(&lh[tgt[i] >> BSHIFT], 1);
    __syncthreads();
    if (tid < nbuck) gh[tid * NBLK + blk] = lh[tid];
}

// ---------------- scan kernels (cell table; boff folded into consumers) ----------------

__global__ __launch_bounds__(256) void k_scanA(const int* __restrict__ deg,
                                               int* __restrict__ excl,
                                               int* __restrict__ bsum, int n) {
    int i = blockIdx.x * 256 + threadIdx.x;
    int lane = threadIdx.x & 63, wv = threadIdx.x >> 6;
    int v = (i < n) ? deg[i] : 0;
    int incl = v;
#pragma unroll
    for (int off = 1; off < 64; off <<= 1) {
        int t = __shfl_up(incl, off);
        if (lane >= off) incl += t;
    }
    __shared__ int ws[4];
    if (lane == 63) ws[wv] = incl;
    __syncthreads();
    int prefix = 0;
    for (int k = 0; k < wv; ++k) prefix += ws[k];
    if (i < n) excl[i] = prefix + incl - v;
    if (threadIdx.x == 255) bsum[blockIdx.x] = prefix + incl;
}

__global__ __launch_bounds__(256) void k_scanB(const int* __restrict__ bsum, int* __restrict__ boff,
                                               int nb) {
    __shared__ int ws[4];
    __shared__ int carry_s;
    int lane = threadIdx.x & 63, wv = threadIdx.x >> 6;
    if (threadIdx.x == 0) carry_s = 0;
    __syncthreads();
    for (int base = 0; base < nb; base += 256) {
        int i = base + threadIdx.x;
        int v = (i < nb) ? bsum[i] : 0;
        int incl = v;
#pragma unroll
        for (int off = 1; off < 64; off <<= 1) {
            int t = __shfl_up(incl, off);
            if (lane >= off) incl += t;
        }
        if (lane == 63) ws[wv] = incl;
        __syncthreads();
        int prefix = carry_s;
        for (int k = 0; k < wv; ++k) prefix += ws[k];
        if (i < nb) boff[i] = prefix + incl - v;
        __syncthreads();
        if (threadIdx.x == 255) carry_s = prefix + incl;
        __syncthreads();
    }
}

// ---------------- Pass 2: block-dense bucket placement (no global atomics) ----------------

__global__ __launch_bounds__(256) void k_binplace(const int* __restrict__ src,
                                                  const int* __restrict__ tgt,
                                                  const float* __restrict__ ea,
                                                  const float* __restrict__ x,
                                                  const int* __restrict__ gexcl,
                                                  const int* __restrict__ gboff,
                                                  float4* __restrict__ brec,
                                                  int* __restrict__ bmeta,
                                                  int e, int chunk, int nbuck) {
    __shared__ int loff[256];
    int tid = threadIdx.x, blk = blockIdx.x;
    if (tid < nbuck) {
        int cell = tid * NBLK + blk;
        loff[tid] = gexcl[cell] + gboff[cell >> 8];
    }
    __syncthreads();
    int lo = blk * chunk, hi = min(lo + chunk, e);
    for (int i = lo + tid; i < hi; i += 256) {
        int t = tgt[i], s = src[i];
        float2 ev = ((const float2*)ea)[i];
        float2 xv = *(const float2*)(x + 2 * (size_t)s);
        int dst = atomicAdd(&loff[t >> BSHIFT], 1);
        brec[dst] = make_float4(xv.x, xv.y, ev.x, ev.y);     // {x[src], ea}
        bmeta[dst] = (s & 0xFFFF) | ((t & BMASK) << 16);     // src16 | tgt_local8
    }
}

// ---------------- fused: per-bucket degree hist + scan + rowp + CSR placement ----------------

__global__ __launch_bounds__(256) void k_place2(const int* __restrict__ gexcl,
                                                const int* __restrict__ gboff,
                                                const int* __restrict__ bmeta,
                                                const float4* __restrict__ brec,
                                                float4* __restrict__ col_rec,
                                                unsigned short* __restrict__ col_src,
                                                int* __restrict__ rowp,
                                                int n, int ntot, int e) {
    __shared__ int hist[256];
    __shared__ int pos[256];
    __shared__ int ws[4];
    int b = blockIdx.x, tid = threadIdx.x;
    int clo = b * NBLK, chi = clo + NBLK;
    int lo = gexcl[clo] + gboff[clo >> 8];
    int hi = (chi >= ntot) ? e : (gexcl[chi] + gboff[chi >> 8]);
    hist[tid] = 0;
    __syncthreads();
    for (int i = lo + tid; i < hi; i += 256)
        atomicAdd(&hist[(bmeta[i] >> 16) & BMASK], 1);
    __syncthreads();
    int lane = tid & 63, wv = tid >> 6;
    int v = hist[tid];
    int incl = v;
#pragma unroll
    for (int off = 1; off < 64; off <<= 1) {
        int t = __shfl_up(incl, off);
        if (lane >= off) incl += t;
    }
    if (lane == 63) ws[wv] = incl;
    __syncthreads();
    int prefix = 0;
    for (int k = 0; k < wv; ++k) prefix += ws[k];
    int rp = lo + prefix + incl - v;
    int node = b * 256 + tid;
    if (node <= n) rowp[node] = rp;
    if (b == (int)gridDim.x - 1 && tid == 255) rowp[n] = hi;
    pos[tid] = rp;
    __syncthreads();
    for (int i = lo + tid; i < hi; i += 256) {
        int m = bmeta[i];
        float4 r = brec[i];
        int slot = atomicAdd(&pos[(m >> 16) & BMASK], 1);
        col_rec[slot] = r;
        col_src[slot] = (unsigned short)(m & 0xFFFF);
    }
}

// ---------------- Layer 1: linearized no-max softmax aggregation (8-edge batched) ----------------
// wave per node; lane l owns features 2l,2l+1; head = l>>2 (4-lane quad groups).
// Output per node: 16 head-pairs q=(px0,px1)/lh + deg>0 flag; hpost reconstructed in k_transform2.

__global__ __launch_bounds__(256) void k_agg1(
    const float* __restrict__ x,
    const int* __restrict__ rowp,
    const float4* __restrict__ col_rec,
    const float* __restrict__ W_l1, const float* __restrict__ b_l1,
    const float* __restrict__ W_r1, const float* __restrict__ b_r1,
    const float* __restrict__ W_e1,
    const float* __restrict__ att1,
    float2* __restrict__ qbuf,       // [n*16]
    int* __restrict__ flags,         // [n]
    int n)
{
    int wid = (blockIdx.x * blockDim.x + threadIdx.x) >> 6;
    if (wid >= n) return;
    int v = __builtin_amdgcn_readfirstlane(wid);
    int lane = threadIdx.x & 63;
    int f0 = 2 * lane, f1 = 2 * lane + 1;

    float Wl00 = W_l1[f0], Wl10 = W_l1[128 + f0];
    float Wl01 = W_l1[f1], Wl11 = W_l1[128 + f1];
    float We00 = W_e1[f0], We10 = W_e1[128 + f0];
    float We01 = W_e1[f1], We11 = W_e1[128 + f1];
    float a0 = att1[f0], a1 = att1[f1];

    float xv0 = x[2 * v], xv1 = x[2 * v + 1];
    float cA = fmaf(xv0, W_r1[f0], fmaf(xv1, W_r1[128 + f0], b_r1[f0])) + b_l1[f0];
    float cB = fmaf(xv0, W_r1[f1], fmaf(xv1, W_r1[128 + f1], b_r1[f1])) + b_l1[f1];

    float lh = 0.f, px0 = 0.f, px1 = 0.f;
    int rs = rowp[v], re = rowp[v + 1];
    bool b0 = (lane & 1) != 0, b1 = (lane & 2) != 0;

    int cs = rs;
#define E1(K, R) \
    float s##K; { \
        float m0 = fmaf(R.x, Wl00, fmaf(R.y, Wl10, fmaf(R.z, We00, fmaf(R.w, We10, cA)))); \
        float m1 = fmaf(R.x, Wl01, fmaf(R.y, Wl11, fmaf(R.z, We01, fmaf(R.w, We11, cB)))); \
        s##K = quadsum(fmaf(fmaxf(m0, 0.2f * m0), a0, fmaxf(m1, 0.2f * m1) * a1)); \
    }
    for (; cs + 8 <= re; cs += 8) {           // 8 independent rec loads in flight
        float4 r0 = col_rec[cs + 0];
        float4 r1 = col_rec[cs + 1];
        float4 r2 = col_rec[cs + 2];
        float4 r3 = col_rec[cs + 3];
        float4 r4 = col_rec[cs + 4];
        float4 r5 = col_rec[cs + 5];
        float4 r6 = col_rec[cs + 6];
        float4 r7 = col_rec[cs + 7];
        E1(0, r0) E1(1, r1) E1(2, r2) E1(3, r3)
        E1(4, r4) E1(5, r5) E1(6, r6) E1(7, r7)
        float smyA = b1 ? (b0 ? s3 : s2) : (b0 ? s1 : s0);
        float smyB = b1 ? (b0 ? s7 : s6) : (b0 ? s5 : s4);
        float pA = __expf(smyA);
        float pB = __expf(smyB);
        float p0 = dppf<0x00>(pA), p1 = dppf<0x55>(pA), p2 = dppf<0xAA>(pA), p3 = dppf<0xFF>(pA);
        float p4 = dppf<0x00>(pB), p5 = dppf<0x55>(pB), p6 = dppf<0xAA>(pB), p7 = dppf<0xFF>(pB);
        lh += ((p0 + p1) + (p2 + p3)) + ((p4 + p5) + (p6 + p7));
        px0 = fmaf(p0, r0.x, px0); px0 = fmaf(p1, r1.x, px0);
        px0 = fmaf(p2, r2.x, px0); px0 = fmaf(p3, r3.x, px0);
        px0 = fmaf(p4, r4.x, px0); px0 = fmaf(p5, r5.x, px0);
        px0 = fmaf(p6, r6.x, px0); px0 = fmaf(p7, r7.x, px0);
        px1 = fmaf(p0, r0.y, px1); px1 = fmaf(p1, r1.y, px1);
        px1 = fmaf(p2, r2.y, px1); px1 = fmaf(p3, r3.y, px1);
        px1 = fmaf(p4, r4.y, px1); px1 = fmaf(p5, r5.y, px1);
        px1 = fmaf(p6, r6.y, px1); px1 = fmaf(p7, r7.y, px1);
    }
    if (cs + 4 <= re) {
        float4 r0 = col_rec[cs + 0];
        float4 r1 = col_rec[cs + 1];
        float4 r2 = col_rec[cs + 2];
        float4 r3 = col_rec[cs + 3];
        E1(0, r0) E1(1, r1) E1(2, r2) E1(3, r3)
        float smy = b1 ? (b0 ? s3 : s2) : (b0 ? s1 : s0);
        float p = __expf(smy);
        float p0 = dppf<0x00>(p), p1 = dppf<0x55>(p), p2 = dppf<0xAA>(p), p3 = dppf<0xFF>(p);
        lh += (p0 + p1) + (p2 + p3);
        px0 = fmaf(p0, r0.x, px0); px0 = fmaf(p1, r1.x, px0);
        px0 = fmaf(p2, r2.x, px0); px0 = fmaf(p3, r3.x, px0);
        px1 = fmaf(p0, r0.y, px1); px1 = fmaf(p1, r1.y, px1);
        px1 = fmaf(p2, r2.y, px1); px1 = fmaf(p3, r3.y, px1);
        cs += 4;
    }
    for (; cs < re; ++cs) {                 // tail (<=3 edges); s quad-uniform, no bcast
        float4 r = col_rec[cs];
        float m0 = fmaf(r.x, Wl00, fmaf(r.y, Wl10, fmaf(r.z, We00, fmaf(r.w, We10, cA))));
        float m1 = fmaf(r.x, Wl01, fmaf(r.y, Wl11, fmaf(r.z, We01, fmaf(r.w, We11, cB))));
        float s = quadsum(fmaf(fmaxf(m0, 0.2f * m0), a0, fmaxf(m1, 0.2f * m1) * a1));
        float p = __expf(s);
        lh += p;
        px0 = fmaf(p, r.x, px0);
        px1 = fmaf(p, r.y, px1);
    }
#undef E1

    float inv = (re > rs) ? 1.f / lh : 0.f;
    if ((lane & 3) == 0)
        qbuf[(size_t)v * 16 + (lane >> 2)] = make_float2(px0 * inv, px1 * inv);
    if (lane == 0) flags[v] = (re > rs) ? 1 : 0;
}

// ---------------- Layer 2 node transforms: register-tiled LDS GEMM ----------------
// hpost reconstructed on-the-fly from q: h = elu(q0*Wl0[f] + q1*Wl1[f] + flag*bl[f] + bias[f])

struct XF2Shared {
    float4 hs[64 * 32];
    float4 ws[128 * 16];
};

__device__ __forceinline__ void xf2_pass(XF2Shared& sm,
                                         const float* __restrict__ W,
                                         const float* __restrict__ b,
                                         float* __restrict__ out,
                                         int v0, int n, int t) {
    __syncthreads();
    {
        const float4* wsrc = (const float4*)W;
#pragma unroll
        for (int i = 0; i < 8; ++i) sm.ws[t + 256 * i] = wsrc[t + 256 * i];
    }
    __syncthreads();

    int lane = t & 63, w = t >> 6;
    int fg = lane & 3, ng = lane >> 2;
    int fq = 4 * w + fg;
    int hsw = ng & 7;

    float acc[4][4];
#pragma unroll
    for (int i = 0; i < 4; ++i)
#pragma unroll
        for (int c = 0; c < 4; ++c) acc[i][c] = 0.f;

    for (int kq = 0; kq < 32; ++kq) {
        float4 w0 = sm.ws[(4 * kq + 0) * 16 + fq];
        float4 w1 = sm.ws[(4 * kq + 1) * 16 + fq];
        float4 w2 = sm.ws[(4 * kq + 2) * 16 + fq];
        float4 w3 = sm.ws[(4 * kq + 3) * 16 + fq];
        int ks = kq ^ hsw;
        float4 h0 = sm.hs[(4 * ng + 0) * 32 + ks];
        float4 h1 = sm.hs[(4 * ng + 1) * 32 + ks];
        float4 h2 = sm.hs[(4 * ng + 2) * 32 + ks];
        float4 h3 = sm.hs[(4 * ng + 3) * 32 + ks];
#pragma unroll
        for (int i = 0; i < 4; ++i) {
            float4 h = (i == 0) ? h0 : (i == 1) ? h1 : (i == 2) ? h2 : h3;
            acc[i][0] += h.x * w0.x; acc[i][1] += h.x * w0.y; acc[i][2] += h.x * w0.z; acc[i][3] += h.x * w0.w;
            acc[i][0] += h.y * w1.x; acc[i][1] += h.y * w1.y; acc[i][2] += h.y * w1.z; acc[i][3] += h.y * w1.w;
            acc[i][0] += h.z * w2.x; acc[i][1] += h.z * w2.y; acc[i][2] += h.z * w2.z; acc[i][3] += h.z * w2.w;
            acc[i][0] += h.w * w3.x; acc[i][1] += h.w * w3.y; acc[i][2] += h.w * w3.z; acc[i][3] += h.w * w3.w;
        }
    }

    float4 bf = ((const float4*)b)[fq];
#pragma unroll
    for (int i = 0; i < 4; ++i) {
        int node = v0 + 4 * ng + i;
        if (node < n) {
            float4 r = make_float4(acc[i][0] + bf.x, acc[i][1] + bf.y,
                                   acc[i][2] + bf.z, acc[i][3] + bf.w);
            *(float4*)(out + (size_t)node * 64 + 4 * fq) = r;
        }
    }
}

__device__ __forceinline__ float elu1(float v) {
    return (v > 0.f) ? v : (__expf(v) - 1.f);
}

__global__ __launch_bounds__(256) void k_transform2(
    const float2* __restrict__ qbuf, const int* __restrict__ flags,
    const float* __restrict__ W_l1, const float* __restrict__ b_l1,
    const float* __restrict__ bias1,
    const float* __restrict__ W_l2, const float* __restrict__ b_l2,
    const float* __restrict__ W_r2, const float* __restrict__ b_r2,
    float* __restrict__ xl2, float* __restrict__ xr2, int n)
{
    __shared__ XF2Shared sm;
    int t = threadIdx.x;
    int v0 = blockIdx.x * 64;
    {
        int node = t >> 2, sub = t & 3;
        int sw = (node >> 2) & 7;
        int gn = v0 + node;
        bool valid = gn < n;
        int fl = valid ? flags[gn] : 0;
        const float4* wl0 = (const float4*)W_l1;           // row 0
        const float4* wl1 = (const float4*)(W_l1 + 128);   // row 1
        const float4* blp = (const float4*)b_l1;
        const float4* bip = (const float4*)bias1;
        float flf = (float)fl;
#pragma unroll
        for (int i = 0; i < 8; ++i) {
            int kq = sub + 4 * i;
            float2 q = valid ? qbuf[(size_t)gn * 16 + (kq >> 1)] : make_float2(0.f, 0.f);
            float4 w0 = wl0[kq], w1 = wl1[kq];
            float4 bl = blp[kq], bi = bip[kq];
            float4 val;
            val.x = elu1(fmaf(q.x, w0.x, fmaf(q.y, w1.x, fmaf(flf, bl.x, bi.x))));
            val.y = elu1(fmaf(q.x, w0.y, fmaf(q.y, w1.y, fmaf(flf, bl.y, bi.y))));
            val.z = elu1(fmaf(q.x, w0.z, fmaf(q.y, w1.z, fmaf(flf, bl.z, bi.z))));
            val.w = elu1(fmaf(q.x, w0.w, fmaf(q.y, w1.w, fmaf(flf, bl.w, bi.w))));
            if (!valid) val = make_float4(0.f, 0.f, 0.f, 0.f);
            sm.hs[node * 32 + (kq ^ sw)] = val;
        }
    }
    xf2_pass(sm, W_l2, b_l2, xl2, v0, n, t);
    xf2_pass(sm, W_r2, b_r2, xr2, v0, n, t);
}

// ---------------- Layer 2 aggregation: no-max softmax (8-edge batched MLP) ----------------
// wave per node, lane = feature; head = lane>>4 (16-lane groups)

__global__ __launch_bounds__(256) void k_agg2(
    const float* __restrict__ xl2,
    const float* __restrict__ xr2,
    const int* __restrict__ rowp,
    const unsigned short* __restrict__ col_src,
    const float4* __restrict__ col_rec,
    const float* __restrict__ W_e2,
    const float* __restrict__ att2,
    const float* __restrict__ bias2,
    float* __restrict__ h2,
    int n)
{
    int wid = (blockIdx.x * blockDim.x + threadIdx.x) >> 6;
    if (wid >= n) return;
    int v = __builtin_amdgcn_readfirstlane(wid);
    int lane = threadIdx.x & 63;
    float We0 = W_e2[lane], We1 = W_e2[64 + lane];
    float a = att2[lane];
    float xr = xr2[(size_t)v * 64 + lane];
    float lh = 0.f, acc = 0.f;
    int rs = rowp[v], re = rowp[v + 1];
    const float2* eap = (const float2*)col_rec;   // {ea0,ea1} at odd float2 slots
    bool b0 = (lane & 1) != 0, b1 = (lane & 2) != 0;

    int cs = rs;
#define E2(K, EV, XL) \
    float s##K; { \
        float m = fmaf(EV.x, We0, fmaf(EV.y, We1, XL + xr)); \
        s##K = sum16(fmaxf(m, 0.2f * m) * a); \
    }
    for (; cs + 8 <= re; cs += 8) {           // 8 independent xl2 gathers in flight
        int u0 = col_src[cs + 0], u1 = col_src[cs + 1], u2 = col_src[cs + 2], u3 = col_src[cs + 3];
        int u4 = col_src[cs + 4], u5 = col_src[cs + 5], u6 = col_src[cs + 6], u7 = col_src[cs + 7];
        float xl0 = xl2[(size_t)u0 * 64 + lane];
        float xl1 = xl2[(size_t)u1 * 64 + lane];
        float xl2_ = xl2[(size_t)u2 * 64 + lane];
        float xl3 = xl2[(size_t)u3 * 64 + lane];
        float xl4 = xl2[(size_t)u4 * 64 + lane];
        float xl5 = xl2[(size_t)u5 * 64 + lane];
        float xl6 = xl2[(size_t)u6 * 64 + lane];
        float xl7 = xl2[(size_t)u7 * 64 + lane];
        float2 e0 = eap[2 * cs + 1], e1 = eap[2 * cs + 3];
        float2 e2 = eap[2 * cs + 5], e3 = eap[2 * cs + 7];
        float2 e4 = eap[2 * cs + 9], e5 = eap[2 * cs + 11];
        float2 e6 = eap[2 * cs + 13], e7 = eap[2 * cs + 15];
        E2(0, e0, xl0) E2(1, e1, xl1) E2(2, e2, xl2_) E2(3, e3, xl3)
        E2(4, e4, xl4) E2(5, e5, xl5) E2(6, e6, xl6) E2(7, e7, xl7)
        float smyA = b1 ? (b0 ? s3 : s2) : (b0 ? s1 : s0);
        float smyB = b1 ? (b0 ? s7 : s6) : (b0 ? s5 : s4);
        float pA = __expf(smyA);
        float pB = __expf(smyB);
        float p0 = dppf<0x00>(pA), p1 = dppf<0x55>(pA), p2 = dppf<0xAA>(pA), p3 = dppf<0xFF>(pA);
        float p4 = dppf<0x00>(pB), p5 = dppf<0x55>(pB), p6 = dppf<0xAA>(pB), p7 = dppf<0xFF>(pB);
        lh += ((p0 + p1) + (p2 + p3)) + ((p4 + p5) + (p6 + p7));
        acc = fmaf(p0, xl0, acc); acc = fmaf(p1, xl1, acc);
        acc = fmaf(p2, xl2_, acc); acc = fmaf(p3, xl3, acc);
        acc = fmaf(p4, xl4, acc); acc = fmaf(p5, xl5, acc);
        acc = fmaf(p6, xl6, acc); acc = fmaf(p7, xl7, acc);
    }
    if (cs + 4 <= re) {
        int u0 = col_src[cs + 0], u1 = col_src[cs + 1], u2 = col_src[cs + 2], u3 = col_src[cs + 3];
        float2 e0 = eap[2 * cs + 1], e1 = eap[2 * cs + 3];
        float2 e2 = eap[2 * cs + 5], e3 = eap[2 * cs + 7];
        float xl0 = xl2[(size_t)u0 * 64 + lane];
        float xl1 = xl2[(size_t)u1 * 64 + lane];
        float xl2_ = xl2[(size_t)u2 * 64 + lane];
        float xl3 = xl2[(size_t)u3 * 64 + lane];
        E2(0, e0, xl0) E2(1, e1, xl1) E2(2, e2, xl2_) E2(3, e3, xl3)
        float smy = b1 ? (b0 ? s3 : s2) : (b0 ? s1 : s0);
        float p = __expf(smy);
        float p0 = dppf<0x00>(p), p1 = dppf<0x55>(p), p2 = dppf<0xAA>(p), p3 = dppf<0xFF>(p);
        lh += (p0 + p1) + (p2 + p3);
        acc = fmaf(p0, xl0, acc); acc = fmaf(p1, xl1, acc);
        acc = fmaf(p2, xl2_, acc); acc = fmaf(p3, xl3, acc);
        cs += 4;
    }
    for (; cs < re; ++cs) {
        int u = col_src[cs];
        float2 ev = eap[2 * cs + 1];
        float xl = xl2[(size_t)u * 64 + lane];
        float m = fmaf(ev.x, We0, fmaf(ev.y, We1, xl + xr));
        float s = sum16(fmaxf(m, 0.2f * m) * a);
        float p = __expf(s);
        lh += p;
        acc = fmaf(p, xl, acc);
    }
#undef E2
    float r = (re > rs) ? acc / lh : 0.f;
    h2[(size_t)v * 64 + lane] = r + bias2[lane];
}

// ---------------- Mean pool over graphs (batch sorted: segmented reduce) ----------------

__global__ __launch_bounds__(256) void k_pool2(const float* __restrict__ h2,
                                               const int* __restrict__ batch,
                                               float* __restrict__ sums, float* __restrict__ cnt,
                                               int n, int chunk) {
    int w = (blockIdx.x * blockDim.x + threadIdx.x) >> 6;
    int lane = threadIdx.x & 63;
    int start = w * chunk;
    if (start >= n) return;
    int end = min(n, start + chunk);
    int g = batch[start];
    float acc = 0.f;
    int c = 0;
    for (int v = start; v < end; ++v) {
        int bg = batch[v];
        if (bg != g) {
            atomicAdd(&sums[g * 64 + lane], acc);
            if (lane == 0) atomicAdd(&cnt[g], (float)c);
            acc = 0.f; c = 0; g = bg;
        }
        acc += h2[(size_t)v * 64 + lane];
        ++c;
    }
    atomicAdd(&sums[g * 64 + lane], acc);
    if (lane == 0) atomicAdd(&cnt[g], (float)c);
}

__global__ void k_final(const float* __restrict__ sums, const float* __restrict__ cnt,
                        float* __restrict__ out, int g) {
    int i = blockIdx.x * blockDim.x + threadIdx.x;
    if (i < g * 64) out[i] = sums[i] / fmaxf(cnt[i >> 6], 1.f);
}

// ---------------- launch ----------------

extern "C" void kernel_launch(void* const* d_in, const int* in_sizes, int n_in,
                              void* d_out, int out_size, void* d_ws, size_t ws_size,
                              hipStream_t stream) {
    const float* x     = (const float*)d_in[0];
    const float* ea    = (const float*)d_in[1];
    const float* W_l1  = (const float*)d_in[2];
    const float* b_l1  = (const float*)d_in[3];
    const float* W_r1  = (const float*)d_in[4];
    const float* b_r1  = (const float*)d_in[5];
    const float* W_e1  = (const float*)d_in[6];
    const float* att1  = (const float*)d_in[7];
    const float* bias1 = (const float*)d_in[8];
    const float* W_l2  = (const float*)d_in[9];
    const float* b_l2  = (const float*)d_in[10];
    const float* W_r2  = (const float*)d_in[11];
    const float* b_r2  = (const float*)d_in[12];
    const float* W_e2  = (const float*)d_in[13];
    const float* att2  = (const float*)d_in[14];
    const float* bias2 = (const float*)d_in[15];
    const int* eidx    = (const int*)d_in[16];
    const int* batch   = (const int*)d_in[17];

    int n = in_sizes[0] / 2;     // 50000
    int e = in_sizes[16] / 2;    // 800000
    int g = out_size / 64;       // 64
    const int* srcI = eidx;
    const int* tgtI = eidx + e;
    int nb = (n + 255) / 256;    // 196 buckets (256 nodes each)
    int ntot = nb * NBLK;        // cell table size
    int nb2 = (ntot + 255) / 256;
    int chunk = (e + NBLK - 1) / NBLK;

    char* w = (char*)d_ws;
    size_t off = 0;
    auto take = [&](size_t bytes) -> char* {
        size_t a = (off + 255) & ~(size_t)255;
        off = a + bytes;
        return w + a;
    };
    // region1: brec (sort phase) then h2 (agg2 output)
    char*   reg1    = take((size_t)e * 16);             // 12.8 MB
    float4* brec    = (float4*)reg1;
    float*  h2      = (float*)reg1;
    // region2: bmeta (sort phase) then xl2 (transform2..agg2)
    char*   reg2    = take((size_t)n * 64 * 4);         // 12.8 MB >= e*4
    int*    bmeta   = (int*)reg2;
    float*  xl2     = (float*)reg2;

    float*  xr2     = (float*)take((size_t)n * 64 * 4);
    float4* col_rec = (float4*)take((size_t)e * 16);
    unsigned short* col_src = (unsigned short*)take((size_t)e * 2);
    int*    rowp    = (int*)take((size_t)(n + 1) * 4);
    float2* qbuf    = (float2*)take((size_t)n * 16 * 8);
    int*    flags   = (int*)take((size_t)n * 4);
    int*    gh      = (int*)take((size_t)ntot * 4);
    int*    gexcl   = (int*)take((size_t)(ntot + 1) * 4);
    int*    gbsum   = (int*)take((size_t)nb2 * 4);
    int*    gboff   = (int*)take((size_t)nb2 * 4);
    float*  sums    = (float*)take((size_t)g * 64 * 4);
    float*  cnt     = (float*)take((size_t)g * 4);

    // dense two-pass counting sort by (bucket, block); k_hist also zero-inits pool accum
    k_hist<<<NBLK, 256, 0, stream>>>(tgtI, gh, sums, cnt, g, e, chunk, nb);
    k_scanA<<<nb2, 256, 0, stream>>>(gh, gexcl, gbsum, ntot);
    k_scanB<<<1, 256, 0, stream>>>(gbsum, gboff, nb2);
    k_binplace<<<NBLK, 256, 0, stream>>>(srcI, tgtI, ea, x, gexcl, gboff, brec, bmeta,
                                         e, chunk, nb);
    k_place2<<<nb, 256, 0, stream>>>(gexcl, gboff, bmeta, brec, col_rec, col_src, rowp,
                                     n, ntot, e);

    int nwaveblocks = (n * 64 + 255) / 256;
    k_agg1<<<nwaveblocks, 256, 0, stream>>>(x, rowp, col_rec,
                                            W_l1, b_l1, W_r1, b_r1, W_e1, att1,
                                            qbuf, flags, n);
    int ntiles = (n + 63) / 64;
    k_transform2<<<ntiles, 256, 0, stream>>>(qbuf, flags, W_l1, b_l1, bias1,
                                             W_l2, b_l2, W_r2, b_r2, xl2, xr2, n);
    k_agg2<<<nwaveblocks, 256, 0, stream>>>(xl2, xr2, rowp, col_src, col_rec,
                                            W_e2, att2, bias2, h2, n);

    int pool_waves = 1024;
    int pool_chunk = (n + pool_waves - 1) / pool_waves;
    k_pool2<<<pool_waves / 4, 256, 0, stream>>>(h2, batch, sums, cnt, n, pool_chunk);
    k_final<<<(g * 64 + 255) / 256, 256, 0, stream>>>(sums, cnt, (float*)d_out, g);
}

// Round 16
// 174.336 us; speedup vs baseline: 1.0378x; 1.0008x over previous
//
#include <hip/hip_runtime.h>
#include <math.h>

#define NBLK 512     // bucketing blocks (each owns a contiguous edge chunk)
#define BSHIFT 8     // 256 nodes per bucket
#define BMASK 255

// ---------------- DPP helpers (full-rate VALU cross-lane, no LDS) ----------------

template<int CTRL>
__device__ __forceinline__ float dppf(float x) {
    return __int_as_float(__builtin_amdgcn_update_dpp(
        0, __float_as_int(x), CTRL, 0xF, 0xF, true));
}
// sum over 4-lane quad (lanes end with identical value)
__device__ __forceinline__ float quadsum(float x) {
    x += dppf<0xB1>(x);   // quad_perm xor 1
    x += dppf<0x4E>(x);   // quad_perm xor 2
    return x;
}
// sum over 16-lane group
__device__ __forceinline__ float sum16(float x) {
    x += dppf<0xB1>(x);
    x += dppf<0x4E>(x);
    x += dppf<0x141>(x);  // row_half_mirror
    x += dppf<0x140>(x);  // row_mirror
    return x;
}

// ---------------- Pass 1: per-(bucket,block) histogram, LDS only ----------------
// block 0 also zero-fills the pool accumulators (replaces k_init / memset).

__global__ __launch_bounds__(256) void k_hist(const int* __restrict__ tgt,
                                              int* __restrict__ gh,
                                              float* __restrict__ sums,
                                              float* __restrict__ cnt, int gn,
                                              int e, int chunk, int nbuck) {
    __shared__ int lh[256];
    int tid = threadIdx.x, blk = blockIdx.x;
    if (blk == 0) {
        for (int i = tid; i < gn * 64; i += 256) sums[i] = 0.f;
        for (int i = tid; i < gn; i += 256) cnt[i] = 0.f;
    }
    lh[tid] = 0;
    __syncthreads();
    int lo = blk * chunk, hi = min(lo + chunk, e);
    for (int i = lo + tid; i < hi; i += 256)
        atomicAdd(&lh[tgt[i] >> BSHIFT], 1);
    __syncthreads();
    if (tid < nbuck) gh[tid * NBLK + blk] = lh[tid];
}

// ---------------- scan kernels (cell table; boff folded into consumers) ----------------

__global__ __launch_bounds__(256) void k_scanA(const int* __restrict__ deg,
                                               int* __restrict__ excl,
                                               int* __restrict__ bsum, int n) {
    int i = blockIdx.x * 256 + threadIdx.x;
    int lane = threadIdx.x & 63, wv = threadIdx.x >> 6;
    int v = (i < n) ? deg[i] : 0;
    int incl = v;
#pragma unroll
    for (int off = 1; off < 64; off <<= 1) {
        int t = __shfl_up(incl, off);
        if (lane >= off) incl += t;
    }
    __shared__ int ws[4];
    if (lane == 63) ws[wv] = incl;
    __syncthreads();
    int prefix = 0;
    for (int k = 0; k < wv; ++k) prefix += ws[k];
    if (i < n) excl[i] = prefix + incl - v;
    if (threadIdx.x == 255) bsum[blockIdx.x] = prefix + incl;
}

__global__ __launch_bounds__(256) void k_scanB(const int* __restrict__ bsum, int* __restrict__ boff,
                                               int nb) {
    __shared__ int ws[4];
    __shared__ int carry_s;
    int lane = threadIdx.x & 63, wv = threadIdx.x >> 6;
    if (threadIdx.x == 0) carry_s = 0;
    __syncthreads();
    for (int base = 0; base < nb; base += 256) {
        int i = base + threadIdx.x;
        int v = (i < nb) ? bsum[i] : 0;
        int incl = v;
#pragma unroll
        for (int off = 1; off < 64; off <<= 1) {
            int t = __shfl_up(incl, off);
            if (lane >= off) incl += t;
        }
        if (lane == 63) ws[wv] = incl;
        __syncthreads();
        int prefix = carry_s;
        for (int k = 0; k < wv; ++k) prefix += ws[k];
        if (i < nb) boff[i] = prefix + incl - v;
        __syncthreads();
        if (threadIdx.x == 255) carry_s = prefix + incl;
        __syncthreads();
    }
}

// ---------------- Pass 2: block-dense bucket placement (no global atomics) ----------------

__global__ __launch_bounds__(256) void k_binplace(const int* __restrict__ src,
                                                  const int* __restrict__ tgt,
                                                  const float* __restrict__ ea,
                                                  const float* __restrict__ x,
                                                  const int* __restrict__ gexcl,
                                                  const int* __restrict__ gboff,
                                                  float4* __restrict__ brec,
                                                  int* __restrict__ bmeta,
                                                  int e, int chunk, int nbuck) {
    __shared__ int loff[256];
    int tid = threadIdx.x, blk = blockIdx.x;
    if (tid < nbuck) {
        int cell = tid * NBLK + blk;
        loff[tid] = gexcl[cell] + gboff[cell >> 8];
    }
    __syncthreads();
    int lo = blk * chunk, hi = min(lo + chunk, e);
    for (int i = lo + tid; i < hi; i += 256) {
        int t = tgt[i], s = src[i];
        float2 ev = ((const float2*)ea)[i];
        float2 xv = *(const float2*)(x + 2 * (size_t)s);
        int dst = atomicAdd(&loff[t >> BSHIFT], 1);
        brec[dst] = make_float4(xv.x, xv.y, ev.x, ev.y);     // {x[src], ea}
        bmeta[dst] = (s & 0xFFFF) | ((t & BMASK) << 16);     // src16 | tgt_local8
    }
}

// ---------------- fused: per-bucket degree hist + scan + rowp + CSR placement ----------------

__global__ __launch_bounds__(256) void k_place2(const int* __restrict__ gexcl,
                                                const int* __restrict__ gboff,
                                                const int* __restrict__ bmeta,
                                                const float4* __restrict__ brec,
                                                float4* __restrict__ col_rec,
                                                unsigned short* __restrict__ col_src,
                                                int* __restrict__ rowp,
                                                int n, int ntot, int e) {
    __shared__ int hist[256];
    __shared__ int pos[256];
    __shared__ int ws[4];
    int b = blockIdx.x, tid = threadIdx.x;
    int clo = b * NBLK, chi = clo + NBLK;
    int lo = gexcl[clo] + gboff[clo >> 8];
    int hi = (chi >= ntot) ? e : (gexcl[chi] + gboff[chi >> 8]);
    hist[tid] = 0;
    __syncthreads();
    for (int i = lo + tid; i < hi; i += 256)
        atomicAdd(&hist[(bmeta[i] >> 16) & BMASK], 1);
    __syncthreads();
    int lane = tid & 63, wv = tid >> 6;
    int v = hist[tid];
    int incl = v;
#pragma unroll
    for (int off = 1; off < 64; off <<= 1) {
        int t = __shfl_up(incl, off);
        if (lane >= off) incl += t;
    }
    if (lane == 63) ws[wv] = incl;
    __syncthreads();
    int prefix = 0;
    for (int k = 0; k < wv; ++k) prefix += ws[k];
    int rp = lo + prefix + incl - v;
    int node = b * 256 + tid;
    if (node <= n) rowp[node] = rp;
    if (b == (int)gridDim.x - 1 && tid == 255) rowp[n] = hi;
    pos[tid] = rp;
    __syncthreads();
    for (int i = lo + tid; i < hi; i += 256) {
        int m = bmeta[i];
        float4 r = brec[i];
        int slot = atomicAdd(&pos[(m >> 16) & BMASK], 1);
        col_rec[slot] = r;
        col_src[slot] = (unsigned short)(m & 0xFFFF);
    }
}

// ---------------- Layer 1: linearized no-max softmax aggregation (8-edge batched) ----------------
// wave per node; lane l owns features 2l,2l+1; head = l>>2 (4-lane quad groups).
// Output per node: 16 head-pairs q=(px0,px1)/lh + deg>0 flag; hpost reconstructed in k_transform2.

__global__ __launch_bounds__(256) void k_agg1(
    const float* __restrict__ x,
    const int* __restrict__ rowp,
    const float4* __restrict__ col_rec,
    const float* __restrict__ W_l1, const float* __restrict__ b_l1,
    const float* __restrict__ W_r1, const float* __restrict__ b_r1,
    const float* __restrict__ W_e1,
    const float* __restrict__ att1,
    float2* __restrict__ qbuf,       // [n*16]
    int* __restrict__ flags,         // [n]
    int n)
{
    int wid = (blockIdx.x * blockDim.x + threadIdx.x) >> 6;
    if (wid >= n) return;
    int v = __builtin_amdgcn_readfirstlane(wid);
    int lane = threadIdx.x & 63;
    int f0 = 2 * lane, f1 = 2 * lane + 1;

    float Wl00 = W_l1[f0], Wl10 = W_l1[128 + f0];
    float Wl01 = W_l1[f1], Wl11 = W_l1[128 + f1];
    float We00 = W_e1[f0], We10 = W_e1[128 + f0];
    float We01 = W_e1[f1], We11 = W_e1[128 + f1];
    float a0 = att1[f0], a1 = att1[f1];

    float xv0 = x[2 * v], xv1 = x[2 * v + 1];
    float cA = fmaf(xv0, W_r1[f0], fmaf(xv1, W_r1[128 + f0], b_r1[f0])) + b_l1[f0];
    float cB = fmaf(xv0, W_r1[f1], fmaf(xv1, W_r1[128 + f1], b_r1[f1])) + b_l1[f1];

    float lh = 0.f, px0 = 0.f, px1 = 0.f;
    int rs = rowp[v], re = rowp[v + 1];
    bool b0 = (lane & 1) != 0, b1 = (lane & 2) != 0;

    int cs = rs;
#define E1(K, R) \
    float s##K; { \
        float m0 = fmaf(R.x, Wl00, fmaf(R.y, Wl10, fmaf(R.z, We00, fmaf(R.w, We10, cA)))); \
        float m1 = fmaf(R.x, Wl01, fmaf(R.y, Wl11, fmaf(R.z, We01, fmaf(R.w, We11, cB)))); \
        s##K = quadsum(fmaf(fmaxf(m0, 0.2f * m0), a0, fmaxf(m1, 0.2f * m1) * a1)); \
    }
    for (; cs + 8 <= re; cs += 8) {           // 8 independent rec loads in flight
        float4 r0 = col_rec[cs + 0];
        float4 r1 = col_rec[cs + 1];
        float4 r2 = col_rec[cs + 2];
        float4 r3 = col_rec[cs + 3];
        float4 r4 = col_rec[cs + 4];
        float4 r5 = col_rec[cs + 5];
        float4 r6 = col_rec[cs + 6];
        float4 r7 = col_rec[cs + 7];
        E1(0, r0) E1(1, r1) E1(2, r2) E1(3, r3)
        E1(4, r4) E1(5, r5) E1(6, r6) E1(7, r7)
        float smyA = b1 ? (b0 ? s3 : s2) : (b0 ? s1 : s0);
        float smyB = b1 ? (b0 ? s7 : s6) : (b0 ? s5 : s4);
        float pA = __expf(smyA);
        float pB = __expf(smyB);
        float p0 = dppf<0x00>(pA), p1 = dppf<0x55>(pA), p2 = dppf<0xAA>(pA), p3 = dppf<0xFF>(pA);
        float p4 = dppf<0x00>(pB), p5 = dppf<0x55>(pB), p6 = dppf<0xAA>(pB), p7 = dppf<0xFF>(pB);
        lh += ((p0 + p1) + (p2 + p3)) + ((p4 + p5) + (p6 + p7));
        px0 = fmaf(p0, r0.x, px0); px0 = fmaf(p1, r1.x, px0);
        px0 = fmaf(p2, r2.x, px0); px0 = fmaf(p3, r3.x, px0);
        px0 = fmaf(p4, r4.x, px0); px0 = fmaf(p5, r5.x, px0);
        px0 = fmaf(p6, r6.x, px0); px0 = fmaf(p7, r7.x, px0);
        px1 = fmaf(p0, r0.y, px1); px1 = fmaf(p1, r1.y, px1);
        px1 = fmaf(p2, r2.y, px1); px1 = fmaf(p3, r3.y, px1);
        px1 = fmaf(p4, r4.y, px1); px1 = fmaf(p5, r5.y, px1);
        px1 = fmaf(p6, r6.y, px1); px1 = fmaf(p7, r7.y, px1);
    }
    if (cs + 4 <= re) {
        float4 r0 = col_rec[cs + 0];
        float4 r1 = col_rec[cs + 1];
        float4 r2 = col_rec[cs + 2];
        float4 r3 = col_rec[cs + 3];
        E1(0, r0) E1(1, r1) E1(2, r2) E1(3, r3)
        float smy = b1 ? (b0 ? s3 : s2) : (b0 ? s1 : s0);
        float p = __expf(smy);
        float p0 = dppf<0x00>(p), p1 = dppf<0x55>(p), p2 = dppf<0xAA>(p), p3 = dppf<0xFF>(p);
        lh += (p0 + p1) + (p2 + p3);
        px0 = fmaf(p0, r0.x, px0); px0 = fmaf(p1, r1.x, px0);
        px0 = fmaf(p2, r2.x, px0); px0 = fmaf(p3, r3.x, px0);
        px1 = fmaf(p0, r0.y, px1); px1 = fmaf(p1, r1.y, px1);
        px1 = fmaf(p2, r2.y, px1); px1 = fmaf(p3, r3.y, px1);
        cs += 4;
    }
    for (; cs < re; ++cs) {                 // tail (<=3 edges); s quad-uniform, no bcast
        float4 r = col_rec[cs];
        float m0 = fmaf(r.x, Wl00, fmaf(r.y, Wl10, fmaf(r.z, We00, fmaf(r.w, We10, cA))));
        float m1 = fmaf(r.x, Wl01, fmaf(r.y, Wl11, fmaf(r.z, We01, fmaf(r.w, We11, cB))));
        float s = quadsum(fmaf(fmaxf(m0, 0.2f * m0), a0, fmaxf(m1, 0.2f * m1) * a1));
        float p = __expf(s);
        lh += p;
        px0 = fmaf(p, r.x, px0);
        px1 = fmaf(p, r.y, px1);
    }
#undef E1

    float inv = (re > rs) ? 1.f / lh : 0.f;
    if ((lane & 3) == 0)
        qbuf[(size_t)v * 16 + (lane >> 2)] = make_float2(px0 * inv, px1 * inv);
    if (lane == 0) flags[v] = (re > rs) ? 1 : 0;
}

// ---------------- Layer 2 node transforms: register-tiled LDS GEMM ----------------
// hpost reconstructed on-the-fly from q. ws staged in 32-row quarters (8KB):
// LDS = 32KB hs + 8KB ws = 40KB -> 4 blocks/CU (vs 2 at 64KB) -> single grid wave.

struct XF2Shared {
    float4 hs[64 * 32];   // 32 KB
    float4 ws[32 * 16];   // 8 KB (one quarter of W)
};

__device__ __forceinline__ void xf2_pass(XF2Shared& sm,
                                         const float* __restrict__ W,
                                         const float* __restrict__ b,
                                         float* __restrict__ out,
                                         int v0, int n, int t) {
    int lane = t & 63, w = t >> 6;
    int fg = lane & 3, ng = lane >> 2;
    int fq = 4 * w + fg;
    int hsw = ng & 7;

    float acc[4][4];
#pragma unroll
    for (int i = 0; i < 4; ++i)
#pragma unroll
        for (int c = 0; c < 4; ++c) acc[i][c] = 0.f;

    const float4* wsrc = (const float4*)W;
    for (int qtr = 0; qtr < 4; ++qtr) {
        __syncthreads();                         // previous reads done
        sm.ws[t]       = wsrc[qtr * 512 + t];
        sm.ws[t + 256] = wsrc[qtr * 512 + t + 256];
        __syncthreads();
#pragma unroll
        for (int k8 = 0; k8 < 8; ++k8) {
            int kq = qtr * 8 + k8;
            float4 w0 = sm.ws[(4 * k8 + 0) * 16 + fq];
            float4 w1 = sm.ws[(4 * k8 + 1) * 16 + fq];
            float4 w2 = sm.ws[(4 * k8 + 2) * 16 + fq];
            float4 w3 = sm.ws[(4 * k8 + 3) * 16 + fq];
            int ks = kq ^ hsw;
            float4 h0 = sm.hs[(4 * ng + 0) * 32 + ks];
            float4 h1 = sm.hs[(4 * ng + 1) * 32 + ks];
            float4 h2 = sm.hs[(4 * ng + 2) * 32 + ks];
            float4 h3 = sm.hs[(4 * ng + 3) * 32 + ks];
#pragma unroll
            for (int i = 0; i < 4; ++i) {
                float4 h = (i == 0) ? h0 : (i == 1) ? h1 : (i == 2) ? h2 : h3;
                acc[i][0] += h.x * w0.x; acc[i][1] += h.x * w0.y; acc[i][2] += h.x * w0.z; acc[i][3] += h.x * w0.w;
                acc[i][0] += h.y * w1.x; acc[i][1] += h.y * w1.y; acc[i][2] += h.y * w1.z; acc[i][3] += h.y * w1.w;
                acc[i][0] += h.z * w2.x; acc[i][1] += h.z * w2.y; acc[i][2] += h.z * w2.z; acc[i][3] += h.z * w2.w;
                acc[i][0] += h.w * w3.x; acc[i][1] += h.w * w3.y; acc[i][2] += h.w * w3.z; acc[i][3] += h.w * w3.w;
            }
        }
    }

    float4 bf = ((const float4*)b)[fq];
#pragma unroll
    for (int i = 0; i < 4; ++i) {
        int node = v0 + 4 * ng + i;
        if (node < n) {
            float4 r = make_float4(acc[i][0] + bf.x, acc[i][1] + bf.y,
                                   acc[i][2] + bf.z, acc[i][3] + bf.w);
            *(float4*)(out + (size_t)node * 64 + 4 * fq) = r;
        }
    }
}

__device__ __forceinline__ float elu1(float v) {
    return (v > 0.f) ? v : (__expf(v) - 1.f);
}

__global__ __launch_bounds__(256) void k_transform2(
    const float2* __restrict__ qbuf, const int* __restrict__ flags,
    const float* __restrict__ W_l1, const float* __restrict__ b_l1,
    const float* __restrict__ bias1,
    const float* __restrict__ W_l2, const float* __restrict__ b_l2,
    const float* __restrict__ W_r2, const float* __restrict__ b_r2,
    float* __restrict__ xl2, float* __restrict__ xr2, int n)
{
    __shared__ XF2Shared sm;
    int t = threadIdx.x;
    int v0 = blockIdx.x * 64;
    {
        int node = t >> 2, sub = t & 3;
        int sw = (node >> 2) & 7;
        int gn = v0 + node;
        bool valid = gn < n;
        int fl = valid ? flags[gn] : 0;
        const float4* wl0 = (const float4*)W_l1;           // row 0
        const float4* wl1 = (const float4*)(W_l1 + 128);   // row 1
        const float4* blp = (const float4*)b_l1;
        const float4* bip = (const float4*)bias1;
        float flf = (float)fl;
#pragma unroll
        for (int i = 0; i < 8; ++i) {
            int kq = sub + 4 * i;
            float2 q = valid ? qbuf[(size_t)gn * 16 + (kq >> 1)] : make_float2(0.f, 0.f);
            float4 w0 = wl0[kq], w1 = wl1[kq];
            float4 bl = blp[kq], bi = bip[kq];
            float4 val;
            val.x = elu1(fmaf(q.x, w0.x, fmaf(q.y, w1.x, fmaf(flf, bl.x, bi.x))));
            val.y = elu1(fmaf(q.x, w0.y, fmaf(q.y, w1.y, fmaf(flf, bl.y, bi.y))));
            val.z = elu1(fmaf(q.x, w0.z, fmaf(q.y, w1.z, fmaf(flf, bl.z, bi.z))));
            val.w = elu1(fmaf(q.x, w0.w, fmaf(q.y, w1.w, fmaf(flf, bl.w, bi.w))));
            if (!valid) val = make_float4(0.f, 0.f, 0.f, 0.f);
            sm.hs[node * 32 + (kq ^ sw)] = val;
        }
    }
    xf2_pass(sm, W_l2, b_l2, xl2, v0, n, t);
    xf2_pass(sm, W_r2, b_r2, xr2, v0, n, t);
}

// ---------------- Layer 2 aggregation: no-max softmax (8-edge batched MLP) ----------------
// wave per node, lane = feature; head = lane>>4 (16-lane groups)

__global__ __launch_bounds__(256) void k_agg2(
    const float* __restrict__ xl2,
    const float* __restrict__ xr2,
    const int* __restrict__ rowp,
    const unsigned short* __restrict__ col_src,
    const float4* __restrict__ col_rec,
    const float* __restrict__ W_e2,
    const float* __restrict__ att2,
    const float* __restrict__ bias2,
    float* __restrict__ h2,
    int n)
{
    int wid = (blockIdx.x * blockDim.x + threadIdx.x) >> 6;
    if (wid >= n) return;
    int v = __builtin_amdgcn_readfirstlane(wid);
    int lane = threadIdx.x & 63;
    float We0 = W_e2[lane], We1 = W_e2[64 + lane];
    float a = att2[lane];
    float xr = xr2[(size_t)v * 64 + lane];
    float lh = 0.f, acc = 0.f;
    int rs = rowp[v], re = rowp[v + 1];
    const float2* eap = (const float2*)col_rec;   // {ea0,ea1} at odd float2 slots
    bool b0 = (lane & 1) != 0, b1 = (lane & 2) != 0;

    int cs = rs;
#define E2(K, EV, XL) \
    float s##K; { \
        float m = fmaf(EV.x, We0, fmaf(EV.y, We1, XL + xr)); \
        s##K = sum16(fmaxf(m, 0.2f * m) * a); \
    }
    for (; cs + 8 <= re; cs += 8) {           // 8 independent xl2 gathers in flight
        int u0 = col_src[cs + 0], u1 = col_src[cs + 1], u2 = col_src[cs + 2], u3 = col_src[cs + 3];
        int u4 = col_src[cs + 4], u5 = col_src[cs + 5], u6 = col_src[cs + 6], u7 = col_src[cs + 7];
        float xl0 = xl2[(size_t)u0 * 64 + lane];
        float xl1 = xl2[(size_t)u1 * 64 + lane];
        float xl2_ = xl2[(size_t)u2 * 64 + lane];
        float xl3 = xl2[(size_t)u3 * 64 + lane];
        float xl4 = xl2[(size_t)u4 * 64 + lane];
        float xl5 = xl2[(size_t)u5 * 64 + lane];
        float xl6 = xl2[(size_t)u6 * 64 + lane];
        float xl7 = xl2[(size_t)u7 * 64 + lane];
        float2 e0 = eap[2 * cs + 1], e1 = eap[2 * cs + 3];
        float2 e2 = eap[2 * cs + 5], e3 = eap[2 * cs + 7];
        float2 e4 = eap[2 * cs + 9], e5 = eap[2 * cs + 11];
        float2 e6 = eap[2 * cs + 13], e7 = eap[2 * cs + 15];
        E2(0, e0, xl0) E2(1, e1, xl1) E2(2, e2, xl2_) E2(3, e3, xl3)
        E2(4, e4, xl4) E2(5, e5, xl5) E2(6, e6, xl6) E2(7, e7, xl7)
        float smyA = b1 ? (b0 ? s3 : s2) : (b0 ? s1 : s0);
        float smyB = b1 ? (b0 ? s7 : s6) : (b0 ? s5 : s4);
        float pA = __expf(smyA);
        float pB = __expf(smyB);
        float p0 = dppf<0x00>(pA), p1 = dppf<0x55>(pA), p2 = dppf<0xAA>(pA), p3 = dppf<0xFF>(pA);
        float p4 = dppf<0x00>(pB), p5 = dppf<0x55>(pB), p6 = dppf<0xAA>(pB), p7 = dppf<0xFF>(pB);
        lh += ((p0 + p1) + (p2 + p3)) + ((p4 + p5) + (p6 + p7));
        acc = fmaf(p0, xl0, acc); acc = fmaf(p1, xl1, acc);
        acc = fmaf(p2, xl2_, acc); acc = fmaf(p3, xl3, acc);
        acc = fmaf(p4, xl4, acc); acc = fmaf(p5, xl5, acc);
        acc = fmaf(p6, xl6, acc); acc = fmaf(p7, xl7, acc);
    }
    if (cs + 4 <= re) {
        int u0 = col_src[cs + 0], u1 = col_src[cs + 1], u2 = col_src[cs + 2], u3 = col_src[cs + 3];
        float2 e0 = eap[2 * cs + 1], e1 = eap[2 * cs + 3];
        float2 e2 = eap[2 * cs + 5], e3 = eap[2 * cs + 7];
        float xl0 = xl2[(size_t)u0 * 64 + lane];
        float xl1 = xl2[(size_t)u1 * 64 + lane];
        float xl2_ = xl2[(size_t)u2 * 64 + lane];
        float xl3 = xl2[(size_t)u3 * 64 + lane];
        E2(0, e0, xl0) E2(1, e1, xl1) E2(2, e2, xl2_) E2(3, e3, xl3)
        float smy = b1 ? (b0 ? s3 : s2) : (b0 ? s1 : s0);
        float p = __expf(smy);
        float p0 = dppf<0x00>(p), p1 = dppf<0x55>(p), p2 = dppf<0xAA>(p), p3 = dppf<0xFF>(p);
        lh += (p0 + p1) + (p2 + p3);
        acc = fmaf(p0, xl0, acc); acc = fmaf(p1, xl1, acc);
        acc = fmaf(p2, xl2_, acc); acc = fmaf(p3, xl3, acc);
        cs += 4;
    }
    for (; cs < re; ++cs) {
        int u = col_src[cs];
        float2 ev = eap[2 * cs + 1];
        float xl = xl2[(size_t)u * 64 + lane];
        float m = fmaf(ev.x, We0, fmaf(ev.y, We1, xl + xr));
        float s = sum16(fmaxf(m, 0.2f * m) * a);
        float p = __expf(s);
        lh += p;
        acc = fmaf(p, xl, acc);
    }
#undef E2
    float r = (re > rs) ? acc / lh : 0.f;
    h2[(size_t)v * 64 + lane] = r + bias2[lane];
}

// ---------------- Mean pool over graphs (batch sorted: segmented reduce) ----------------

__global__ __launch_bounds__(256) void k_pool2(const float* __restrict__ h2,
                                               const int* __restrict__ batch,
                                               float* __restrict__ sums, float* __restrict__ cnt,
                                               int n, int chunk) {
    int w = (blockIdx.x * blockDim.x + threadIdx.x) >> 6;
    int lane = threadIdx.x & 63;
    int start = w * chunk;
    if (start >= n) return;
    int end = min(n, start + chunk);
    int g = batch[start];
    float acc = 0.f;
    int c = 0;
    for (int v = start; v < end; ++v) {
        int bg = batch[v];
        if (bg != g) {
            atomicAdd(&sums[g * 64 + lane], acc);
            if (lane == 0) atomicAdd(&cnt[g], (float)c);
            acc = 0.f; c = 0; g = bg;
        }
        acc += h2[(size_t)v * 64 + lane];
        ++c;
    }
    atomicAdd(&sums[g * 64 + lane], acc);
    if (lane == 0) atomicAdd(&cnt[g], (float)c);
}

__global__ void k_final(const float* __restrict__ sums, const float* __restrict__ cnt,
                        float* __restrict__ out, int g) {
    int i = blockIdx.x * blockDim.x + threadIdx.x;
    if (i < g * 64) out[i] = sums[i] / fmaxf(cnt[i >> 6], 1.f);
}

// ---------------- launch ----------------

extern "C" void kernel_launch(void* const* d_in, const int* in_sizes, int n_in,
                              void* d_out, int out_size, void* d_ws, size_t ws_size,
                              hipStream_t stream) {
    const float* x     = (const float*)d_in[0];
    const float* ea    = (const float*)d_in[1];
    const float* W_l1  = (const float*)d_in[2];
    const float* b_l1  = (const float*)d_in[3];
    const float* W_r1  = (const float*)d_in[4];
    const float* b_r1  = (const float*)d_in[5];
    const float* W_e1  = (const float*)d_in[6];
    const float* att1  = (const float*)d_in[7];
    const float* bias1 = (const float*)d_in[8];
    const float* W_l2  = (const float*)d_in[9];
    const float* b_l2  = (const float*)d_in[10];
    const float* W_r2  = (const float*)d_in[11];
    const float* b_r2  = (const float*)d_in[12];
    const float* W_e2  = (const float*)d_in[13];
    const float* att2  = (const float*)d_in[14];
    const float* bias2 = (const float*)d_in[15];
    const int* eidx    = (const int*)d_in[16];
    const int* batch   = (const int*)d_in[17];

    int n = in_sizes[0] / 2;     // 50000
    int e = in_sizes[16] / 2;    // 800000
    int g = out_size / 64;       // 64
    const int* srcI = eidx;
    const int* tgtI = eidx + e;
    int nb = (n + 255) / 256;    // 196 buckets (256 nodes each)
    int ntot = nb * NBLK;        // cell table size
    int nb2 = (ntot + 255) / 256;
    int chunk = (e + NBLK - 1) / NBLK;

    char* w = (char*)d_ws;
    size_t off = 0;
    auto take = [&](size_t bytes) -> char* {
        size_t a = (off + 255) & ~(size_t)255;
        off = a + bytes;
        return w + a;
    };
    // region1: brec (sort phase) then h2 (agg2 output)
    char*   reg1    = take((size_t)e * 16);             // 12.8 MB
    float4* brec    = (float4*)reg1;
    float*  h2      = (float*)reg1;
    // region2: bmeta (sort phase) then xl2 (transform2..agg2)
    char*   reg2    = take((size_t)n * 64 * 4);         // 12.8 MB >= e*4
    int*    bmeta   = (int*)reg2;
    float*  xl2     = (float*)reg2;

    float*  xr2     = (float*)take((size_t)n * 64 * 4);
    float4* col_rec = (float4*)take((size_t)e * 16);
    unsigned short* col_src = (unsigned short*)take((size_t)e * 2);
    int*    rowp    = (int*)take((size_t)(n + 1) * 4);
    float2* qbuf    = (float2*)take((size_t)n * 16 * 8);
    int*    flags   = (int*)take((size_t)n * 4);
    int*    gh      = (int*)take((size_t)ntot * 4);
    int*    gexcl   = (int*)take((size_t)(ntot + 1) * 4);
    int*    gbsum   = (int*)take((size_t)nb2 * 4);
    int*    gboff   = (int*)take((size_t)nb2 * 4);
    float*  sums    = (float*)take((size_t)g * 64 * 4);
    float*  cnt     = (float*)take((size_t)g * 4);

    // dense two-pass counting sort by (bucket, block); k_hist also zero-inits pool accum
    k_hist<<<NBLK, 256, 0, stream>>>(tgtI, gh, sums, cnt, g, e, chunk, nb);
    k_scanA<<<nb2, 256, 0, stream>>>(gh, gexcl, gbsum, ntot);
    k_scanB<<<1, 256, 0, stream>>>(gbsum, gboff, nb2);
    k_binplace<<<NBLK, 256, 0, stream>>>(srcI, tgtI, ea, x, gexcl, gboff, brec, bmeta,
                                         e, chunk, nb);
    k_place2<<<nb, 256, 0, stream>>>(gexcl, gboff, bmeta, brec, col_rec, col_src, rowp,
                                     n, ntot, e);

    int nwaveblocks = (n * 64 + 255) / 256;
    k_agg1<<<nwaveblocks, 256, 0, stream>>>(x, rowp, col_rec,
                                            W_l1, b_l1, W_r1, b_r1, W_e1, att1,
                                            qbuf, flags, n);
    int ntiles = (n + 63) / 64;
    k_transform2<<<ntiles, 256, 0, stream>>>(qbuf, flags, W_l1, b_l1, bias1,
                                             W_l2, b_l2, W_r2, b_r2, xl2, xr2, n);
    k_agg2<<<nwaveblocks, 256, 0, stream>>>(xl2, xr2, rowp, col_src, col_rec,
                                            W_e2, att2, bias2, h2, n);

    int pool_waves = 1024;
    int pool_chunk = (n + pool_waves - 1) / pool_waves;
    k_pool2<<<pool_waves / 4, 256, 0, stream>>>(h2, batch, sums, cnt, n, pool_chunk);
    k_final<<<(g * 64 + 255) / 256, 256, 0, stream>>>(sums, cnt, (float*)d_out, g);
}

// Round 17
// 172.945 us; speedup vs baseline: 1.0461x; 1.0080x over previous
//
#include <hip/hip_runtime.h>
#include <math.h>

#define NBLK 512     // bucketing blocks (each owns a contiguous edge chunk)
#define BSHIFT 8     // 256 nodes per bucket
#define BMASK 255

// ---------------- DPP helpers (full-rate VALU cross-lane, no LDS) ----------------

template<int CTRL>
__device__ __forceinline__ float dppf(float x) {
    return __int_as_float(__builtin_amdgcn_update_dpp(
        0, __float_as_int(x), CTRL, 0xF, 0xF, true));
}
// sum over 4-lane quad (lanes end with identical value)
__device__ __forceinline__ float quadsum(float x) {
    x += dppf<0xB1>(x);   // quad_perm xor 1
    x += dppf<0x4E>(x);   // quad_perm xor 2
    return x;
}
// sum over 16-lane group
__device__ __forceinline__ float sum16(float x) {
    x += dppf<0xB1>(x);
    x += dppf<0x4E>(x);
    x += dppf<0x141>(x);  // row_half_mirror
    x += dppf<0x140>(x);  // row_mirror
    return x;
}

// ---------------- Pass 1: per-(bucket,block) histogram, LDS only ----------------
// block 0 also zero-fills the pool accumulators (replaces k_init / memset).

__global__ __launch_bounds__(256) void k_hist(const int* __restrict__ tgt,
                                              int* __restrict__ gh,
                                              float* __restrict__ sums,
                                              float* __restrict__ cnt, int gn,
                                              int e, int chunk, int nbuck) {
    __shared__ int lh[256];
    int tid = threadIdx.x, blk = blockIdx.x;
    if (blk == 0) {
        for (int i = tid; i < gn * 64; i += 256) sums[i] = 0.f;
        for (int i = tid; i < gn; i += 256) cnt[i] = 0.f;
    }
    lh[tid] = 0;
    __syncthreads();
    int lo = blk * chunk, hi = min(lo + chunk, e);
    for (int i = lo + tid; i < hi; i += 256)
        atomicAdd(&lh[tgt[i] >> BSHIFT], 1);
    __syncthreads();
    if (tid < nbuck) gh[tid * NBLK + blk] = lh[tid];
}

// ---------------- scan kernels (cell table; boff folded into consumers) ----------------

__global__ __launch_bounds__(256) void k_scanA(const int* __restrict__ deg,
                                               int* __restrict__ excl,
                                               int* __restrict__ bsum, int n) {
    int i = blockIdx.x * 256 + threadIdx.x;
    int lane = threadIdx.x & 63, wv = threadIdx.x >> 6;
    int v = (i < n) ? deg[i] : 0;
    int incl = v;
#pragma unroll
    for (int off = 1; off < 64; off <<= 1) {
        int t = __shfl_up(incl, off);
        if (lane >= off) incl += t;
    }
    __shared__ int ws[4];
    if (lane == 63) ws[wv] = incl;
    __syncthreads();
    int prefix = 0;
    for (int k = 0; k < wv; ++k) prefix += ws[k];
    if (i < n) excl[i] = prefix + incl - v;
    if (threadIdx.x == 255) bsum[blockIdx.x] = prefix + incl;
}

__global__ __launch_bounds__(256) void k_scanB(const int* __restrict__ bsum, int* __restrict__ boff,
                                               int nb) {
    __shared__ int ws[4];
    __shared__ int carry_s;
    int lane = threadIdx.x & 63, wv = threadIdx.x >> 6;
    if (threadIdx.x == 0) carry_s = 0;
    __syncthreads();
    for (int base = 0; base < nb; base += 256) {
        int i = base + threadIdx.x;
        int v = (i < nb) ? bsum[i] : 0;
        int incl = v;
#pragma unroll
        for (int off = 1; off < 64; off <<= 1) {
            int t = __shfl_up(incl, off);
            if (lane >= off) incl += t;
        }
        if (lane == 63) ws[wv] = incl;
        __syncthreads();
        int prefix = carry_s;
        for (int k = 0; k < wv; ++k) prefix += ws[k];
        if (i < nb) boff[i] = prefix + incl - v;
        __syncthreads();
        if (threadIdx.x == 255) carry_s = prefix + incl;
        __syncthreads();
    }
}

// ---------------- Pass 2: block-dense bucket placement (no global atomics) ----------------

__global__ __launch_bounds__(256) void k_binplace(const int* __restrict__ src,
                                                  const int* __restrict__ tgt,
                                                  const float* __restrict__ ea,
                                                  const float* __restrict__ x,
                                                  const int* __restrict__ gexcl,
                                                  const int* __restrict__ gboff,
                                                  float4* __restrict__ brec,
                                                  int* __restrict__ bmeta,
                                                  int e, int chunk, int nbuck) {
    __shared__ int loff[256];
    int tid = threadIdx.x, blk = blockIdx.x;
    if (tid < nbuck) {
        int cell = tid * NBLK + blk;
        loff[tid] = gexcl[cell] + gboff[cell >> 8];
    }
    __syncthreads();
    int lo = blk * chunk, hi = min(lo + chunk, e);
    for (int i = lo + tid; i < hi; i += 256) {
        int t = tgt[i], s = src[i];
        float2 ev = ((const float2*)ea)[i];
        float2 xv = *(const float2*)(x + 2 * (size_t)s);
        int dst = atomicAdd(&loff[t >> BSHIFT], 1);
        brec[dst] = make_float4(xv.x, xv.y, ev.x, ev.y);     // {x[src], ea}
        bmeta[dst] = (s & 0xFFFF) | ((t & BMASK) << 16);     // src16 | tgt_local8
    }
}

// ---------------- fused: per-bucket degree hist + scan + rowp + CSR placement ----------------

__global__ __launch_bounds__(256) void k_place2(const int* __restrict__ gexcl,
                                                const int* __restrict__ gboff,
                                                const int* __restrict__ bmeta,
                                                const float4* __restrict__ brec,
                                                float4* __restrict__ col_rec,
                                                unsigned short* __restrict__ col_src,
                                                int* __restrict__ rowp,
                                                int n, int ntot, int e) {
    __shared__ int hist[256];
    __shared__ int pos[256];
    __shared__ int ws[4];
    int b = blockIdx.x, tid = threadIdx.x;
    int clo = b * NBLK, chi = clo + NBLK;
    int lo = gexcl[clo] + gboff[clo >> 8];
    int hi = (chi >= ntot) ? e : (gexcl[chi] + gboff[chi >> 8]);
    hist[tid] = 0;
    __syncthreads();
    for (int i = lo + tid; i < hi; i += 256)
        atomicAdd(&hist[(bmeta[i] >> 16) & BMASK], 1);
    __syncthreads();
    int lane = tid & 63, wv = tid >> 6;
    int v = hist[tid];
    int incl = v;
#pragma unroll
    for (int off = 1; off < 64; off <<= 1) {
        int t = __shfl_up(incl, off);
        if (lane >= off) incl += t;
    }
    if (lane == 63) ws[wv] = incl;
    __syncthreads();
    int prefix = 0;
    for (int k = 0; k < wv; ++k) prefix += ws[k];
    int rp = lo + prefix + incl - v;
    int node = b * 256 + tid;
    if (node <= n) rowp[node] = rp;
    if (b == (int)gridDim.x - 1 && tid == 255) rowp[n] = hi;
    pos[tid] = rp;
    __syncthreads();
    for (int i = lo + tid; i < hi; i += 256) {
        int m = bmeta[i];
        float4 r = brec[i];
        int slot = atomicAdd(&pos[(m >> 16) & BMASK], 1);
        col_rec[slot] = r;
        col_src[slot] = (unsigned short)(m & 0xFFFF);
    }
}

// ---------------- Layer 1: linearized no-max softmax aggregation (8-edge batched) ----------------
// wave per node; lane l owns features 2l,2l+1; head = l>>2 (4-lane quad groups).
// Output per node: 16 head-pairs q=(px0,px1)/lh + deg>0 flag; hpost reconstructed in k_transform2.

__global__ __launch_bounds__(256) void k_agg1(
    const float* __restrict__ x,
    const int* __restrict__ rowp,
    const float4* __restrict__ col_rec,
    const float* __restrict__ W_l1, const float* __restrict__ b_l1,
    const float* __restrict__ W_r1, const float* __restrict__ b_r1,
    const float* __restrict__ W_e1,
    const float* __restrict__ att1,
    float2* __restrict__ qbuf,       // [n*16]
    int* __restrict__ flags,         // [n]
    int n)
{
    int wid = (blockIdx.x * blockDim.x + threadIdx.x) >> 6;
    if (wid >= n) return;
    int v = __builtin_amdgcn_readfirstlane(wid);
    int lane = threadIdx.x & 63;
    int f0 = 2 * lane, f1 = 2 * lane + 1;

    float Wl00 = W_l1[f0], Wl10 = W_l1[128 + f0];
    float Wl01 = W_l1[f1], Wl11 = W_l1[128 + f1];
    float We00 = W_e1[f0], We10 = W_e1[128 + f0];
    float We01 = W_e1[f1], We11 = W_e1[128 + f1];
    float a0 = att1[f0], a1 = att1[f1];

    float xv0 = x[2 * v], xv1 = x[2 * v + 1];
    float cA = fmaf(xv0, W_r1[f0], fmaf(xv1, W_r1[128 + f0], b_r1[f0])) + b_l1[f0];
    float cB = fmaf(xv0, W_r1[f1], fmaf(xv1, W_r1[128 + f1], b_r1[f1])) + b_l1[f1];

    float lh = 0.f, px0 = 0.f, px1 = 0.f;
    int rs = rowp[v], re = rowp[v + 1];
    bool b0 = (lane & 1) != 0, b1 = (lane & 2) != 0;

    int cs = rs;
#define E1(K, R) \
    float s##K; { \
        float m0 = fmaf(R.x, Wl00, fmaf(R.y, Wl10, fmaf(R.z, We00, fmaf(R.w, We10, cA)))); \
        float m1 = fmaf(R.x, Wl01, fmaf(R.y, Wl11, fmaf(R.z, We01, fmaf(R.w, We11, cB)))); \
        s##K = quadsum(fmaf(fmaxf(m0, 0.2f * m0), a0, fmaxf(m1, 0.2f * m1) * a1)); \
    }
    for (; cs + 8 <= re; cs += 8) {           // 8 independent rec loads in flight
        float4 r0 = col_rec[cs + 0];
        float4 r1 = col_rec[cs + 1];
        float4 r2 = col_rec[cs + 2];
        float4 r3 = col_rec[cs + 3];
        float4 r4 = col_rec[cs + 4];
        float4 r5 = col_rec[cs + 5];
        float4 r6 = col_rec[cs + 6];
        float4 r7 = col_rec[cs + 7];
        E1(0, r0) E1(1, r1) E1(2, r2) E1(3, r3)
        E1(4, r4) E1(5, r5) E1(6, r6) E1(7, r7)
        float smyA = b1 ? (b0 ? s3 : s2) : (b0 ? s1 : s0);
        float smyB = b1 ? (b0 ? s7 : s6) : (b0 ? s5 : s4);
        float pA = __expf(smyA);
        float pB = __expf(smyB);
        float p0 = dppf<0x00>(pA), p1 = dppf<0x55>(pA), p2 = dppf<0xAA>(pA), p3 = dppf<0xFF>(pA);
        float p4 = dppf<0x00>(pB), p5 = dppf<0x55>(pB), p6 = dppf<0xAA>(pB), p7 = dppf<0xFF>(pB);
        lh += ((p0 + p1) + (p2 + p3)) + ((p4 + p5) + (p6 + p7));
        px0 = fmaf(p0, r0.x, px0); px0 = fmaf(p1, r1.x, px0);
        px0 = fmaf(p2, r2.x, px0); px0 = fmaf(p3, r3.x, px0);
        px0 = fmaf(p4, r4.x, px0); px0 = fmaf(p5, r5.x, px0);
        px0 = fmaf(p6, r6.x, px0); px0 = fmaf(p7, r7.x, px0);
        px1 = fmaf(p0, r0.y, px1); px1 = fmaf(p1, r1.y, px1);
        px1 = fmaf(p2, r2.y, px1); px1 = fmaf(p3, r3.y, px1);
        px1 = fmaf(p4, r4.y, px1); px1 = fmaf(p5, r5.y, px1);
        px1 = fmaf(p6, r6.y, px1); px1 = fmaf(p7, r7.y, px1);
    }
    if (cs + 4 <= re) {
        float4 r0 = col_rec[cs + 0];
        float4 r1 = col_rec[cs + 1];
        float4 r2 = col_rec[cs + 2];
        float4 r3 = col_rec[cs + 3];
        E1(0, r0) E1(1, r1) E1(2, r2) E1(3, r3)
        float smy = b1 ? (b0 ? s3 : s2) : (b0 ? s1 : s0);
        float p = __expf(smy);
        float p0 = dppf<0x00>(p), p1 = dppf<0x55>(p), p2 = dppf<0xAA>(p), p3 = dppf<0xFF>(p);
        lh += (p0 + p1) + (p2 + p3);
        px0 = fmaf(p0, r0.x, px0); px0 = fmaf(p1, r1.x, px0);
        px0 = fmaf(p2, r2.x, px0); px0 = fmaf(p3, r3.x, px0);
        px1 = fmaf(p0, r0.y, px1); px1 = fmaf(p1, r1.y, px1);
        px1 = fmaf(p2, r2.y, px1); px1 = fmaf(p3, r3.y, px1);
        cs += 4;
    }
    for (; cs < re; ++cs) {                 // tail (<=3 edges); s quad-uniform, no bcast
        float4 r = col_rec[cs];
        float m0 = fmaf(r.x, Wl00, fmaf(r.y, Wl10, fmaf(r.z, We00, fmaf(r.w, We10, cA))));
        float m1 = fmaf(r.x, Wl01, fmaf(r.y, Wl11, fmaf(r.z, We01, fmaf(r.w, We11, cB))));
        float s = quadsum(fmaf(fmaxf(m0, 0.2f * m0), a0, fmaxf(m1, 0.2f * m1) * a1));
        float p = __expf(s);
        lh += p;
        px0 = fmaf(p, r.x, px0);
        px1 = fmaf(p, r.y, px1);
    }
#undef E1

    float inv = (re > rs) ? 1.f / lh : 0.f;
    if ((lane & 3) == 0)
        qbuf[(size_t)v * 16 + (lane >> 2)] = make_float2(px0 * inv, px1 * inv);
    if (lane == 0) flags[v] = (re > rs) ? 1 : 0;
}

// ---------------- Layer 2 node transforms: fused dual-output register-tiled LDS GEMM ----------
// hpost reconstructed on-the-fly from q. Wl+Wr quarters staged together (16KB);
// ONE hs traversal produces both xl2 and xr2: LDS reads halved, barriers halved,
// FMA:LDS ratio doubled. LDS = 32KB hs + 16KB ws = 48KB -> 3 blocks/CU.

struct XF2Shared {
    float4 hs[64 * 32];    // 32 KB
    float4 wsl[32 * 16];   // 8 KB (Wl quarter)
    float4 wsr[32 * 16];   // 8 KB (Wr quarter)
};

__device__ __forceinline__ float elu1(float v) {
    return (v > 0.f) ? v : (__expf(v) - 1.f);
}

__global__ __launch_bounds__(256) void k_transform2(
    const float2* __restrict__ qbuf, const int* __restrict__ flags,
    const float* __restrict__ W_l1, const float* __restrict__ b_l1,
    const float* __restrict__ bias1,
    const float* __restrict__ W_l2, const float* __restrict__ b_l2,
    const float* __restrict__ W_r2, const float* __restrict__ b_r2,
    float* __restrict__ xl2, float* __restrict__ xr2, int n)
{
    __shared__ XF2Shared sm;
    int t = threadIdx.x;
    int v0 = blockIdx.x * 64;
    {
        int node = t >> 2, sub = t & 3;
        int sw = (node >> 2) & 7;
        int gn = v0 + node;
        bool valid = gn < n;
        int fl = valid ? flags[gn] : 0;
        const float4* wl0 = (const float4*)W_l1;           // row 0
        const float4* wl1 = (const float4*)(W_l1 + 128);   // row 1
        const float4* blp = (const float4*)b_l1;
        const float4* bip = (const float4*)bias1;
        float flf = (float)fl;
#pragma unroll
        for (int i = 0; i < 8; ++i) {
            int kq = sub + 4 * i;
            float2 q = valid ? qbuf[(size_t)gn * 16 + (kq >> 1)] : make_float2(0.f, 0.f);
            float4 w0 = wl0[kq], w1 = wl1[kq];
            float4 bl = blp[kq], bi = bip[kq];
            float4 val;
            val.x = elu1(fmaf(q.x, w0.x, fmaf(q.y, w1.x, fmaf(flf, bl.x, bi.x))));
            val.y = elu1(fmaf(q.x, w0.y, fmaf(q.y, w1.y, fmaf(flf, bl.y, bi.y))));
            val.z = elu1(fmaf(q.x, w0.z, fmaf(q.y, w1.z, fmaf(flf, bl.z, bi.z))));
            val.w = elu1(fmaf(q.x, w0.w, fmaf(q.y, w1.w, fmaf(flf, bl.w, bi.w))));
            if (!valid) val = make_float4(0.f, 0.f, 0.f, 0.f);
            sm.hs[node * 32 + (kq ^ sw)] = val;
        }
    }

    int lane = t & 63, w = t >> 6;
    int fg = lane & 3, ng = lane >> 2;
    int fq = 4 * w + fg;
    int hsw = ng & 7;

    float accL[4][4], accR[4][4];
#pragma unroll
    for (int i = 0; i < 4; ++i)
#pragma unroll
        for (int c = 0; c < 4; ++c) { accL[i][c] = 0.f; accR[i][c] = 0.f; }

    const float4* wlsrc = (const float4*)W_l2;
    const float4* wrsrc = (const float4*)W_r2;
    for (int qtr = 0; qtr < 4; ++qtr) {
        __syncthreads();                         // hs staged / previous quarter's reads done
        sm.wsl[t]       = wlsrc[qtr * 512 + t];
        sm.wsl[t + 256] = wlsrc[qtr * 512 + t + 256];
        sm.wsr[t]       = wrsrc[qtr * 512 + t];
        sm.wsr[t + 256] = wrsrc[qtr * 512 + t + 256];
        __syncthreads();
#pragma unroll
        for (int k8 = 0; k8 < 8; ++k8) {
            int kq = qtr * 8 + k8;
            float4 w0 = sm.wsl[(4 * k8 + 0) * 16 + fq];
            float4 w1 = sm.wsl[(4 * k8 + 1) * 16 + fq];
            float4 w2 = sm.wsl[(4 * k8 + 2) * 16 + fq];
            float4 w3 = sm.wsl[(4 * k8 + 3) * 16 + fq];
            float4 v0_ = sm.wsr[(4 * k8 + 0) * 16 + fq];
            float4 v1_ = sm.wsr[(4 * k8 + 1) * 16 + fq];
            float4 v2_ = sm.wsr[(4 * k8 + 2) * 16 + fq];
            float4 v3_ = sm.wsr[(4 * k8 + 3) * 16 + fq];
            int ks = kq ^ hsw;
            float4 h0 = sm.hs[(4 * ng + 0) * 32 + ks];
            float4 h1 = sm.hs[(4 * ng + 1) * 32 + ks];
            float4 h2 = sm.hs[(4 * ng + 2) * 32 + ks];
            float4 h3 = sm.hs[(4 * ng + 3) * 32 + ks];
#pragma unroll
            for (int i = 0; i < 4; ++i) {
                float4 h = (i == 0) ? h0 : (i == 1) ? h1 : (i == 2) ? h2 : h3;
                accL[i][0] += h.x * w0.x; accL[i][1] += h.x * w0.y; accL[i][2] += h.x * w0.z; accL[i][3] += h.x * w0.w;
                accL[i][0] += h.y * w1.x; accL[i][1] += h.y * w1.y; accL[i][2] += h.y * w1.z; accL[i][3] += h.y * w1.w;
                accL[i][0] += h.z * w2.x; accL[i][1] += h.z * w2.y; accL[i][2] += h.z * w2.z; accL[i][3] += h.z * w2.w;
                accL[i][0] += h.w * w3.x; accL[i][1] += h.w * w3.y; accL[i][2] += h.w * w3.z; accL[i][3] += h.w * w3.w;
                accR[i][0] += h.x * v0_.x; accR[i][1] += h.x * v0_.y; accR[i][2] += h.x * v0_.z; accR[i][3] += h.x * v0_.w;
                accR[i][0] += h.y * v1_.x; accR[i][1] += h.y * v1_.y; accR[i][2] += h.y * v1_.z; accR[i][3] += h.y * v1_.w;
                accR[i][0] += h.z * v2_.x; accR[i][1] += h.z * v2_.y; accR[i][2] += h.z * v2_.z; accR[i][3] += h.z * v2_.w;
                accR[i][0] += h.w * v3_.x; accR[i][1] += h.w * v3_.y; accR[i][2] += h.w * v3_.z; accR[i][3] += h.w * v3_.w;
            }
        }
    }

    float4 blf = ((const float4*)b_l2)[fq];
    float4 brf = ((const float4*)b_r2)[fq];
#pragma unroll
    for (int i = 0; i < 4; ++i) {
        int node = v0 + 4 * ng + i;
        if (node < n) {
            float4 rl = make_float4(accL[i][0] + blf.x, accL[i][1] + blf.y,
                                    accL[i][2] + blf.z, accL[i][3] + blf.w);
            float4 rr = make_float4(accR[i][0] + brf.x, accR[i][1] + brf.y,
                                    accR[i][2] + brf.z, accR[i][3] + brf.w);
            *(float4*)(xl2 + (size_t)node * 64 + 4 * fq) = rl;
            *(float4*)(xr2 + (size_t)node * 64 + 4 * fq) = rr;
        }
    }
}

// ---------------- Layer 2 aggregation: no-max softmax (8-edge batched MLP) ----------------
// wave per node, lane = feature; head = lane>>4 (16-lane groups)

__global__ __launch_bounds__(256) void k_agg2(
    const float* __restrict__ xl2,
    const float* __restrict__ xr2,
    const int* __restrict__ rowp,
    const unsigned short* __restrict__ col_src,
    const float4* __restrict__ col_rec,
    const float* __restrict__ W_e2,
    const float* __restrict__ att2,
    const float* __restrict__ bias2,
    float* __restrict__ h2,
    int n)
{
    int wid = (blockIdx.x * blockDim.x + threadIdx.x) >> 6;
    if (wid >= n) return;
    int v = __builtin_amdgcn_readfirstlane(wid);
    int lane = threadIdx.x & 63;
    float We0 = W_e2[lane], We1 = W_e2[64 + lane];
    float a = att2[lane];
    float xr = xr2[(size_t)v * 64 + lane];
    float lh = 0.f, acc = 0.f;
    int rs = rowp[v], re = rowp[v + 1];
    const float2* eap = (const float2*)col_rec;   // {ea0,ea1} at odd float2 slots
    bool b0 = (lane & 1) != 0, b1 = (lane & 2) != 0;

    int cs = rs;
#define E2(K, EV, XL) \
    float s##K; { \
        float m = fmaf(EV.x, We0, fmaf(EV.y, We1, XL + xr)); \
        s##K = sum16(fmaxf(m, 0.2f * m) * a); \
    }
    for (; cs + 8 <= re; cs += 8) {           // 8 independent xl2 gathers in flight
        int u0 = col_src[cs + 0], u1 = col_src[cs + 1], u2 = col_src[cs + 2], u3 = col_src[cs + 3];
        int u4 = col_src[cs + 4], u5 = col_src[cs + 5], u6 = col_src[cs + 6], u7 = col_src[cs + 7];
        float xl0 = xl2[(size_t)u0 * 64 + lane];
        float xl1 = xl2[(size_t)u1 * 64 + lane];
        float xl2_ = xl2[(size_t)u2 * 64 + lane];
        float xl3 = xl2[(size_t)u3 * 64 + lane];
        float xl4 = xl2[(size_t)u4 * 64 + lane];
        float xl5 = xl2[(size_t)u5 * 64 + lane];
        float xl6 = xl2[(size_t)u6 * 64 + lane];
        float xl7 = xl2[(size_t)u7 * 64 + lane];
        float2 e0 = eap[2 * cs + 1], e1 = eap[2 * cs + 3];
        float2 e2 = eap[2 * cs + 5], e3 = eap[2 * cs + 7];
        float2 e4 = eap[2 * cs + 9], e5 = eap[2 * cs + 11];
        float2 e6 = eap[2 * cs + 13], e7 = eap[2 * cs + 15];
        E2(0, e0, xl0) E2(1, e1, xl1) E2(2, e2, xl2_) E2(3, e3, xl3)
        E2(4, e4, xl4) E2(5, e5, xl5) E2(6, e6, xl6) E2(7, e7, xl7)
        float smyA = b1 ? (b0 ? s3 : s2) : (b0 ? s1 : s0);
        float smyB = b1 ? (b0 ? s7 : s6) : (b0 ? s5 : s4);
        float pA = __expf(smyA);
        float pB = __expf(smyB);
        float p0 = dppf<0x00>(pA), p1 = dppf<0x55>(pA), p2 = dppf<0xAA>(pA), p3 = dppf<0xFF>(pA);
        float p4 = dppf<0x00>(pB), p5 = dppf<0x55>(pB), p6 = dppf<0xAA>(pB), p7 = dppf<0xFF>(pB);
        lh += ((p0 + p1) + (p2 + p3)) + ((p4 + p5) + (p6 + p7));
        acc = fmaf(p0, xl0, acc); acc = fmaf(p1, xl1, acc);
        acc = fmaf(p2, xl2_, acc); acc = fmaf(p3, xl3, acc);
        acc = fmaf(p4, xl4, acc); acc = fmaf(p5, xl5, acc);
        acc = fmaf(p6, xl6, acc); acc = fmaf(p7, xl7, acc);
    }
    if (cs + 4 <= re) {
        int u0 = col_src[cs + 0], u1 = col_src[cs + 1], u2 = col_src[cs + 2], u3 = col_src[cs + 3];
        float2 e0 = eap[2 * cs + 1], e1 = eap[2 * cs + 3];
        float2 e2 = eap[2 * cs + 5], e3 = eap[2 * cs + 7];
        float xl0 = xl2[(size_t)u0 * 64 + lane];
        float xl1 = xl2[(size_t)u1 * 64 + lane];
        float xl2_ = xl2[(size_t)u2 * 64 + lane];
        float xl3 = xl2[(size_t)u3 * 64 + lane];
        E2(0, e0, xl0) E2(1, e1, xl1) E2(2, e2, xl2_) E2(3, e3, xl3)
        float smy = b1 ? (b0 ? s3 : s2) : (b0 ? s1 : s0);
        float p = __expf(smy);
        float p0 = dppf<0x00>(p), p1 = dppf<0x55>(p), p2 = dppf<0xAA>(p), p3 = dppf<0xFF>(p);
        lh += (p0 + p1) + (p2 + p3);
        acc = fmaf(p0, xl0, acc); acc = fmaf(p1, xl1, acc);
        acc = fmaf(p2, xl2_, acc); acc = fmaf(p3, xl3, acc);
        cs += 4;
    }
    for (; cs < re; ++cs) {
        int u = col_src[cs];
        float2 ev = eap[2 * cs + 1];
        float xl = xl2[(size_t)u * 64 + lane];
        float m = fmaf(ev.x, We0, fmaf(ev.y, We1, xl + xr));
        float s = sum16(fmaxf(m, 0.2f * m) * a);
        float p = __expf(s);
        lh += p;
        acc = fmaf(p, xl, acc);
    }
#undef E2
    float r = (re > rs) ? acc / lh : 0.f;
    h2[(size_t)v * 64 + lane] = r + bias2[lane];
}

// ---------------- Mean pool over graphs (batch sorted: segmented reduce) ----------------

__global__ __launch_bounds__(256) void k_pool2(const float* __restrict__ h2,
                                               const int* __restrict__ batch,
                                               float* __restrict__ sums, float* __restrict__ cnt,
                                               int n, int chunk) {
    int w = (blockIdx.x * blockDim.x + threadIdx.x) >> 6;
    int lane = threadIdx.x & 63;
    int start = w * chunk;
    if (start >= n) return;
    int end = min(n, start + chunk);
    int g = batch[start];
    float acc = 0.f;
    int c = 0;
    for (int v = start; v < end; ++v) {
        int bg = batch[v];
        if (bg != g) {
            atomicAdd(&sums[g * 64 + lane], acc);
            if (lane == 0) atomicAdd(&cnt[g], (float)c);
            acc = 0.f; c = 0; g = bg;
        }
        acc += h2[(size_t)v * 64 + lane];
        ++c;
    }
    atomicAdd(&sums[g * 64 + lane], acc);
    if (lane == 0) atomicAdd(&cnt[g], (float)c);
}

__global__ void k_final(const float* __restrict__ sums, const float* __restrict__ cnt,
                        float* __restrict__ out, int g) {
    int i = blockIdx.x * blockDim.x + threadIdx.x;
    if (i < g * 64) out[i] = sums[i] / fmaxf(cnt[i >> 6], 1.f);
}

// ---------------- launch ----------------

extern "C" void kernel_launch(void* const* d_in, const int* in_sizes, int n_in,
                              void* d_out, int out_size, void* d_ws, size_t ws_size,
                              hipStream_t stream) {
    const float* x     = (const float*)d_in[0];
    const float* ea    = (const float*)d_in[1];
    const float* W_l1  = (const float*)d_in[2];
    const float* b_l1  = (const float*)d_in[3];
    const float* W_r1  = (const float*)d_in[4];
    const float* b_r1  = (const float*)d_in[5];
    const float* W_e1  = (const float*)d_in[6];
    const float* att1  = (const float*)d_in[7];
    const float* bias1 = (const float*)d_in[8];
    const float* W_l2  = (const float*)d_in[9];
    const float* b_l2  = (const float*)d_in[10];
    const float* W_r2  = (const float*)d_in[11];
    const float* b_r2  = (const float*)d_in[12];
    const float* W_e2  = (const float*)d_in[13];
    const float* att2  = (const float*)d_in[14];
    const float* bias2 = (const float*)d_in[15];
    const int* eidx    = (const int*)d_in[16];
    const int* batch   = (const int*)d_in[17];

    int n = in_sizes[0] / 2;     // 50000
    int e = in_sizes[16] / 2;    // 800000
    int g = out_size / 64;       // 64
    const int* srcI = eidx;
    const int* tgtI = eidx + e;
    int nb = (n + 255) / 256;    // 196 buckets (256 nodes each)
    int ntot = nb * NBLK;        // cell table size
    int nb2 = (ntot + 255) / 256;
    int chunk = (e + NBLK - 1) / NBLK;

    char* w = (char*)d_ws;
    size_t off = 0;
    auto take = [&](size_t bytes) -> char* {
        size_t a = (off + 255) & ~(size_t)255;
        off = a + bytes;
        return w + a;
    };
    // region1: brec (sort phase) then h2 (agg2 output)
    char*   reg1    = take((size_t)e * 16);             // 12.8 MB
    float4* brec    = (float4*)reg1;
    float*  h2      = (float*)reg1;
    // region2: bmeta (sort phase) then xl2 (transform2..agg2)
    char*   reg2    = take((size_t)n * 64 * 4);         // 12.8 MB >= e*4
    int*    bmeta   = (int*)reg2;
    float*  xl2     = (float*)reg2;

    float*  xr2     = (float*)take((size_t)n * 64 * 4);
    float4* col_rec = (float4*)take((size_t)e * 16);
    unsigned short* col_src = (unsigned short*)take((size_t)e * 2);
    int*    rowp    = (int*)take((size_t)(n + 1) * 4);
    float2* qbuf    = (float2*)take((size_t)n * 16 * 8);
    int*    flags   = (int*)take((size_t)n * 4);
    int*    gh      = (int*)take((size_t)ntot * 4);
    int*    gexcl   = (int*)take((size_t)(ntot + 1) * 4);
    int*    gbsum   = (int*)take((size_t)nb2 * 4);
    int*    gboff   = (int*)take((size_t)nb2 * 4);
    float*  sums    = (float*)take((size_t)g * 64 * 4);
    float*  cnt     = (float*)take((size_t)g * 4);

    // dense two-pass counting sort by (bucket, block); k_hist also zero-inits pool accum
    k_hist<<<NBLK, 256, 0, stream>>>(tgtI, gh, sums, cnt, g, e, chunk, nb);
    k_scanA<<<nb2, 256, 0, stream>>>(gh, gexcl, gbsum, ntot);
    k_scanB<<<1, 256, 0, stream>>>(gbsum, gboff, nb2);
    k_binplace<<<NBLK, 256, 0, stream>>>(srcI, tgtI, ea, x, gexcl, gboff, brec, bmeta,
                                         e, chunk, nb);
    k_place2<<<nb, 256, 0, stream>>>(gexcl, gboff, bmeta, brec, col_rec, col_src, rowp,
                                     n, ntot, e);

    int nwaveblocks = (n * 64 + 255) / 256;
    k_agg1<<<nwaveblocks, 256, 0, stream>>>(x, rowp, col_rec,
                                            W_l1, b_l1, W_r1, b_r1, W_e1, att1,
                                            qbuf, flags, n);
    int ntiles = (n + 63) / 64;
    k_transform2<<<ntiles, 256, 0, stream>>>(qbuf, flags, W_l1, b_l1, bias1,
                                             W_l2, b_l2, W_r2, b_r2, xl2, xr2, n);
    k_agg2<<<nwaveblocks, 256, 0, stream>>>(xl2, xr2, rowp, col_src, col_rec,
                                            W_e2, att2, bias2, h2, n);

    int pool_waves = 1024;
    int pool_chunk = (n + pool_waves - 1) / pool_waves;
    k_pool2<<<pool_waves / 4, 256, 0, stream>>>(h2, batch, sums, cnt, n, pool_chunk);
    k_final<<<(g * 64 + 255) / 256, 256, 0, stream>>>(sums, cnt, (float*)d_out, g);
}